// Round 3
// baseline (6096.918 us; speedup 1.0000x reference)
//
#include <hip/hip_runtime.h>
#include <cstdint>
#include <cstddef>

#define DEVI __device__ __forceinline__

namespace {

constexpr int T_B = 128;
constexpr int T_N = 48;
constexpr int NP1 = 49;          // n+1 (ghost node)
constexpr int NOUT = T_B * T_N * 4 * NP1;   // 1,204,224 per output tensor

DEVI unsigned rotl(unsigned x, int d) { return (x << d) | (x >> (32 - d)); }

// JAX threefry, PARTITIONABLE mode (default since jax 0.4.30):
// per-element counter i (uint64 iota) -> block inputs (hi32(i), lo32(i));
// for size < 2^32 that is (0, i). 32-bit output = out0 ^ out1.
DEVI float gumbel_noise(unsigned idx) {
  unsigned x0 = 0u, x1 = idx;
  const unsigned k0 = 0u, k1 = 42u, k2 = 0x1BD11BDAu ^ 0u ^ 42u;
  x0 += k0; x1 += k1;
#define TF_R(rr) { x0 += x1; x1 = rotl(x1, rr); x1 ^= x0; }
  TF_R(13) TF_R(15) TF_R(26) TF_R(6)   x0 += k1; x1 += k2 + 1u;
  TF_R(17) TF_R(29) TF_R(16) TF_R(24)  x0 += k2; x1 += k0 + 2u;
  TF_R(13) TF_R(15) TF_R(26) TF_R(6)   x0 += k0; x1 += k1 + 3u;
  TF_R(17) TF_R(29) TF_R(16) TF_R(24)  x0 += k1; x1 += k2 + 4u;
  TF_R(13) TF_R(15) TF_R(26) TF_R(6)   x0 += k2; x1 += k0 + 5u;
#undef TF_R
  const unsigned bits = x0 ^ x1;
  float u = __uint_as_float((bits >> 9) | 0x3f800000u) - 1.0f;  // [0,1)
  u = fmaxf(u, 0.0f);
  const float ex = -log1pf(-u);   // exponential sample
  return -logf(ex);               // gumbel
}

#define ACC4(ACC, FA, MA, MB, MC, MD)                                   \
  ACC[0] += FA.x * MA.x + FA.y * MB.x + FA.z * MC.x + FA.w * MD.x;      \
  ACC[1] += FA.x * MA.y + FA.y * MB.y + FA.z * MC.y + FA.w * MD.y;      \
  ACC[2] += FA.x * MA.z + FA.y * MB.z + FA.z * MC.z + FA.w * MD.z;      \
  ACC[3] += FA.x * MA.w + FA.y * MB.w + FA.z * MC.w + FA.w * MD.w;

}  // namespace

// One block per (batch, target). Phases:
//  0: stage attn_mask, compute mask_ped, build feat[49][96] in LDS
//  1: E = LayerNorm(feat @ W_embed + b) -> LDS [49][128]
//  2: qkv = E @ W_qkv + b, THREE separate passes (K, V, Q) with one named
//     28-register accumulator each — no runtime-selected private arrays
//     (rule #20: pointer-ternary accumulators went to scratch in R1 and
//     produced 14 GB of HBM spill traffic). K/V store straight to LDS over
//     dead regions; Q is held in regs across one barrier, then overwrites sE.
//  3: per-head wave: scores/softmax/PV/gating in registers, masked em
//     softmax, threefry gumbel, sampled softmax. Writes both outputs.
// LDS arena = 18816 floats (75,264 B) + W1t etc = 79,816 B -> 2 blocks/CU.
__global__ __launch_bounds__(256, 2) void edge_selector_kernel(
    const float* __restrict__ x, const float* __restrict__ A,
    const float* __restrict__ amask, const float* __restrict__ Wemb,
    const float* __restrict__ bemb, const float* __restrict__ gamma_,
    const float* __restrict__ beta_, const float* __restrict__ Wqkv,
    const float* __restrict__ bqkv, const float* __restrict__ W1g,
    const float* __restrict__ b1g, const float* __restrict__ W2g,
    const float* __restrict__ b2g, float* __restrict__ out) {
  __shared__ __align__(16) float F[18816];
  __shared__ __align__(16) float sW1t[32 * 32];  // W1 transposed: [f][e]
  __shared__ float sM[NP1];
  __shared__ float sB1[32];
  __shared__ float sW2s[32];
  __shared__ float sB2;

  float* const sE    = F;             // [49][128]  (phases 1-2)
  float* const sFeat = F + 6272;      // [49][96]   (phases 0-1)
  float* const sAM   = F + 10976;     // [48][48]   (phase 0)
  float* const sMp   = F + 13280;     // [48]       (phase 0)
  float* const sQT   = F;             // [4][32][49] (phase 3, over sE)
  float* const sK    = F + 6272;      // [4][49][32] (phase 3, over sFeat/sAM)
  float* const sV    = F + 12544;     // [4][49][32] (phase 3)

  const int t  = threadIdx.x;
  const int tg = blockIdx.x;
  const int bb = blockIdx.y;

  // ---------------- phase 0a: stage masks & small weights ----------------
  for (int idx = t; idx < 48 * 48; idx += 256) sAM[idx] = amask[bb * 2304 + idx];
  for (int idx = t; idx < 1024; idx += 256) {
    const int e = idx >> 5, f = idx & 31;
    sW1t[f * 32 + e] = W1g[idx];
  }
  if (t < 32) { sB1[t] = b1g[t]; sW2s[t] = W2g[t]; }
  if (t == 0) sB2 = b2g[0];
  __syncthreads();
  if (t < 48) {
    float s = 0.f;
    for (int j = 0; j < 48; ++j) s += sAM[t * 48 + j];
    sMp[t] = (s > 0.f) ? 1.f : 0.f;
    sM[t] = sAM[tg * 48 + t];
  }
  if (t == 0) sM[48] = 1.f;   // ghost column always attendable
  __syncthreads();

  // ---------------- phase 0b: feat = [xn[nb], x[tg], A'[nb,tg]] ----------
  {
    const float mt = sMp[tg];
    for (int idx = t; idx < NP1 * 32; idx += 256) {
      const int nb = idx >> 5, e = idx & 31;
      sFeat[nb * 96 + 32 + e] = x[(bb * 48 + tg) * 32 + e] * mt;
      float xv = 0.f, av = 0.f;
      if (nb < 48) {
        xv = x[(bb * 48 + nb) * 32 + e] * sMp[nb];
        av = A[(((bb * 48 + nb) * 48) + tg) * 32 + e] * sAM[tg * 48 + nb];
      }
      sFeat[nb * 96 + e]      = xv;
      sFeat[nb * 96 + 64 + e] = av;
    }
  }
  __syncthreads();

  const int dq   = t & 31;                 // output column quad (d = dq*4)
  const int nbq  = t >> 5;                 // row group
  const int nrow = (nbq == 0) ? 7 : 6;
  int nbr[7];
#pragma unroll
  for (int r = 0; r < 7; ++r) nbr[r] = (r == 6) ? 48 : (nbq + 8 * r);

  // ---------------- phase 1: E = LN(feat @ Wemb + bemb) ------------------
  {
    float acc[7][4];
#pragma unroll
    for (int r = 0; r < 7; ++r)
#pragma unroll
      for (int c = 0; c < 4; ++c) acc[r][c] = 0.f;

    for (int kc = 0; kc < 96; kc += 8) {
      float4 w[8];
#pragma unroll
      for (int kk = 0; kk < 8; ++kk)
        w[kk] = *(const float4*)&Wemb[(kc + kk) * 128 + dq * 4];
#pragma unroll
      for (int r = 0; r < 7; ++r)
        if (r < nrow) {
          const float* fr = &sFeat[nbr[r] * 96 + kc];
          const float4 fa = *(const float4*)fr;
          const float4 fb = *(const float4*)(fr + 4);
          ACC4(acc[r], fa, w[0], w[1], w[2], w[3]);
          ACC4(acc[r], fb, w[4], w[5], w[6], w[7]);
        }
    }
    const float4 be = *(const float4*)&bemb[dq * 4];
    const float4 gm = *(const float4*)&gamma_[dq * 4];
    const float4 bt = *(const float4*)&beta_[dq * 4];
#pragma unroll
    for (int r = 0; r < 7; ++r)
      if (r < nrow) {
        const float e0 = acc[r][0] + be.x, e1 = acc[r][1] + be.y;
        const float e2 = acc[r][2] + be.z, e3 = acc[r][3] + be.w;
        float s  = e0 + e1 + e2 + e3;
        float qs = e0 * e0 + e1 * e1 + e2 * e2 + e3 * e3;
#pragma unroll
        for (int md = 16; md; md >>= 1) {
          s  += __shfl_xor(s, md, 32);
          qs += __shfl_xor(qs, md, 32);
        }
        const float mu  = s * (1.0f / 128.0f);
        const float var = qs * (1.0f / 128.0f) - mu * mu;
        const float rs  = 1.0f / sqrtf(var + 1e-5f);
        float4 o;
        o.x = (e0 - mu) * rs * gm.x + bt.x;
        o.y = (e1 - mu) * rs * gm.y + bt.y;
        o.z = (e2 - mu) * rs * gm.z + bt.z;
        o.w = (e3 - mu) * rs * gm.w + bt.w;
        *(float4*)&sE[nbr[r] * 128 + dq * 4] = o;
      }
  }
  __syncthreads();

  // ---------------- phase 2: qkv = E @ Wqkv + b, three passes ------------
  const int h  = dq >> 3;
  const int e0c = (dq & 7) * 4;

  // --- K pass: store to sK (over dead sFeat/sAM) ---
  {
    float acc[7][4];
#pragma unroll
    for (int r = 0; r < 7; ++r)
#pragma unroll
      for (int c = 0; c < 4; ++c) acc[r][c] = 0.f;
    for (int kc = 0; kc < 128; kc += 4) {
      float4 ef[7];
#pragma unroll
      for (int r = 0; r < 7; ++r)
        if (r < nrow) ef[r] = *(const float4*)&sE[nbr[r] * 128 + kc];
      const float* wp = &Wqkv[kc * 384 + 128 + dq * 4];
      const float4 w0 = *(const float4*)wp;
      const float4 w1 = *(const float4*)(wp + 384);
      const float4 w2 = *(const float4*)(wp + 768);
      const float4 w3 = *(const float4*)(wp + 1152);
#pragma unroll
      for (int r = 0; r < 7; ++r)
        if (r < nrow) { const float4 f = ef[r]; ACC4(acc[r], f, w0, w1, w2, w3); }
    }
    const float4 bkv = *(const float4*)&bqkv[128 + dq * 4];
#pragma unroll
    for (int r = 0; r < 7; ++r)
      if (r < nrow) {
        float4 ko;
        ko.x = acc[r][0] + bkv.x; ko.y = acc[r][1] + bkv.y;
        ko.z = acc[r][2] + bkv.z; ko.w = acc[r][3] + bkv.w;
        *(float4*)&sK[(h * 49 + nbr[r]) * 32 + e0c] = ko;
      }
  }

  // --- V pass: store to sV ---
  {
    float acc[7][4];
#pragma unroll
    for (int r = 0; r < 7; ++r)
#pragma unroll
      for (int c = 0; c < 4; ++c) acc[r][c] = 0.f;
    for (int kc = 0; kc < 128; kc += 4) {
      float4 ef[7];
#pragma unroll
      for (int r = 0; r < 7; ++r)
        if (r < nrow) ef[r] = *(const float4*)&sE[nbr[r] * 128 + kc];
      const float* wp = &Wqkv[kc * 384 + 256 + dq * 4];
      const float4 w0 = *(const float4*)wp;
      const float4 w1 = *(const float4*)(wp + 384);
      const float4 w2 = *(const float4*)(wp + 768);
      const float4 w3 = *(const float4*)(wp + 1152);
#pragma unroll
      for (int r = 0; r < 7; ++r)
        if (r < nrow) { const float4 f = ef[r]; ACC4(acc[r], f, w0, w1, w2, w3); }
    }
    const float4 bvv = *(const float4*)&bqkv[256 + dq * 4];
#pragma unroll
    for (int r = 0; r < 7; ++r)
      if (r < nrow) {
        float4 vo;
        vo.x = acc[r][0] + bvv.x; vo.y = acc[r][1] + bvv.y;
        vo.z = acc[r][2] + bvv.z; vo.w = acc[r][3] + bvv.w;
        *(float4*)&sV[(h * 49 + nbr[r]) * 32 + e0c] = vo;
      }
  }

  // --- Q pass: accumulate in regs, barrier, then overwrite sE with qT ---
  {
    float acc[7][4];
#pragma unroll
    for (int r = 0; r < 7; ++r)
#pragma unroll
      for (int c = 0; c < 4; ++c) acc[r][c] = 0.f;
    for (int kc = 0; kc < 128; kc += 4) {
      float4 ef[7];
#pragma unroll
      for (int r = 0; r < 7; ++r)
        if (r < nrow) ef[r] = *(const float4*)&sE[nbr[r] * 128 + kc];
      const float* wp = &Wqkv[kc * 384 + dq * 4];
      const float4 w0 = *(const float4*)wp;
      const float4 w1 = *(const float4*)(wp + 384);
      const float4 w2 = *(const float4*)(wp + 768);
      const float4 w3 = *(const float4*)(wp + 1152);
#pragma unroll
      for (int r = 0; r < 7; ++r)
        if (r < nrow) { const float4 f = ef[r]; ACC4(acc[r], f, w0, w1, w2, w3); }
    }
    __syncthreads();  // everyone done reading sE -> safe to overwrite with qT
    const float4 bqv = *(const float4*)&bqkv[dq * 4];
    const float SC = 0.17677669529663687f;  // 1/sqrt(32)
#pragma unroll
    for (int r = 0; r < 7; ++r)
      if (r < nrow) {
        const int nb = nbr[r];
        sQT[(h * 32 + e0c + 0) * 49 + nb] = (acc[r][0] + bqv.x) * SC;
        sQT[(h * 32 + e0c + 1) * 49 + nb] = (acc[r][1] + bqv.y) * SC;
        sQT[(h * 32 + e0c + 2) * 49 + nb] = (acc[r][2] + bqv.z) * SC;
        sQT[(h * 32 + e0c + 3) * 49 + nb] = (acc[r][3] + bqv.w) * SC;
      }
  }
  __syncthreads();

  // ---------------- phase 3: attention + gating + em + sampled -----------
  {
    const int wh   = t >> 6;       // head (one wave per head)
    const int lane = t & 63;
    const bool act = lane < NP1;
    const int i    = act ? lane : 0;

    float qreg[32];
#pragma unroll
    for (int e = 0; e < 32; ++e) qreg[e] = sQT[(wh * 32 + e) * 49 + i];
    const float mi = act ? sM[i] : 0.f;
    const bool mj = act ? (sM[lane] > 0.f) : false;
    const unsigned long long mbits = __ballot(mj);

    float S[NP1];
#pragma unroll
    for (int j = 0; j < NP1; ++j) {
      const float4* kr = (const float4*)&sK[(wh * 49 + j) * 32];
      float a = 0.f;
#pragma unroll
      for (int eq = 0; eq < 8; ++eq) {
        const float4 k4 = kr[eq];
        a += qreg[eq * 4 + 0] * k4.x + qreg[eq * 4 + 1] * k4.y +
             qreg[eq * 4 + 2] * k4.z + qreg[eq * 4 + 3] * k4.w;
      }
      S[j] = a;
    }
    const bool rowok = mi > 0.f;
#pragma unroll
    for (int j = 0; j < NP1; ++j) {
      const bool ok = rowok && ((mbits >> j) & 1ull);
      S[j] = ok ? S[j] : -1e9f;
    }
    float mx = S[0];
#pragma unroll
    for (int j = 1; j < NP1; ++j) mx = fmaxf(mx, S[j]);
    float ssum = 0.f;
#pragma unroll
    for (int j = 0; j < NP1; ++j) { S[j] = expf(S[j] - mx); ssum += S[j]; }
    const float sinv = 1.0f / ssum;
#pragma unroll
    for (int j = 0; j < NP1; ++j) S[j] *= sinv;

    float A2r[32];
#pragma unroll
    for (int e = 0; e < 32; ++e) A2r[e] = 0.f;
#pragma unroll
    for (int j = 0; j < NP1; ++j) {
      const float4* vr = (const float4*)&sV[(wh * 49 + j) * 32];
#pragma unroll
      for (int eq = 0; eq < 8; ++eq) {
        const float4 v4 = vr[eq];
        A2r[eq * 4 + 0] += S[j] * v4.x;
        A2r[eq * 4 + 1] += S[j] * v4.y;
        A2r[eq * 4 + 2] += S[j] * v4.z;
        A2r[eq * 4 + 3] += S[j] * v4.w;
      }
    }

    // gating MLP: s2 = W2 . relu(W1^T A2 + b1) + b2
    float s2 = sB2;
#pragma unroll
    for (int f = 0; f < 32; ++f) {
      const float4* wr = (const float4*)&sW1t[f * 32];
      float a = sB1[f];
#pragma unroll
      for (int eq = 0; eq < 8; ++eq) {
        const float4 w4 = wr[eq];
        a += A2r[eq * 4 + 0] * w4.x + A2r[eq * 4 + 1] * w4.y +
             A2r[eq * 4 + 2] * w4.z + A2r[eq * 4 + 3] * w4.w;
      }
      s2 += fmaxf(a, 0.f) * sW2s[f];
    }

    // em = normalize(softmax_i(s2) * m)
    const float v0 = act ? s2 : -1e30f;
    float mx2 = v0;
#pragma unroll
    for (int md = 32; md; md >>= 1) mx2 = fmaxf(mx2, __shfl_xor(mx2, md));
    float p = act ? expf(v0 - mx2) : 0.f;
    float ps = p;
#pragma unroll
    for (int md = 32; md; md >>= 1) ps += __shfl_xor(ps, md);
    float em = (p / ps) * mi;
    float es = em;
#pragma unroll
    for (int md = 32; md; md >>= 1) es += __shfl_xor(es, md);
    em = em / (es + 1e-10f);

    const int base = ((bb * 48 + tg) * 4 + wh) * 49;
    if (act) out[base + lane] = em;

    // sampled = softmax(log(em + 1e-10) + gumbel)
    const float lg = logf(em + 1e-10f);
    const float gn = gumbel_noise((unsigned)(base + lane));
    const float z = act ? (lg + gn) : -1e30f;
    float mx3 = z;
#pragma unroll
    for (int md = 32; md; md >>= 1) mx3 = fmaxf(mx3, __shfl_xor(mx3, md));
    float p3 = act ? expf(z - mx3) : 0.f;
    float ps3 = p3;
#pragma unroll
    for (int md = 32; md; md >>= 1) ps3 += __shfl_xor(ps3, md);
    if (act) out[NOUT + base + lane] = p3 / ps3;
  }
}

extern "C" void kernel_launch(void* const* d_in, const int* in_sizes, int n_in,
                              void* d_out, int out_size, void* d_ws, size_t ws_size,
                              hipStream_t stream) {
  (void)in_sizes; (void)n_in; (void)out_size; (void)d_ws; (void)ws_size;
  const float* x    = (const float*)d_in[0];
  const float* A    = (const float*)d_in[1];
  const float* am   = (const float*)d_in[2];
  const float* Wemb = (const float*)d_in[3];
  const float* bemb = (const float*)d_in[4];
  const float* gm   = (const float*)d_in[5];
  const float* bt   = (const float*)d_in[6];
  const float* Wqkv = (const float*)d_in[7];
  const float* bqkv = (const float*)d_in[8];
  const float* W1   = (const float*)d_in[9];
  const float* b1   = (const float*)d_in[10];
  const float* W2   = (const float*)d_in[11];
  const float* b2   = (const float*)d_in[12];
  dim3 grid(T_N, T_B);
  edge_selector_kernel<<<grid, 256, 0, stream>>>(
      x, A, am, Wemb, bemb, gm, bt, Wqkv, bqkv, W1, b1, W2, b2, (float*)d_out);
}

// Round 4
// 6094.371 us; speedup vs baseline: 1.0004x; 1.0004x over previous
//
#include <hip/hip_runtime.h>
#include <cstdint>
#include <cstddef>

#define DEVI __device__ __forceinline__

namespace {

constexpr int T_B = 128;
constexpr int T_N = 48;
constexpr int NP1 = 49;          // n+1 (ghost node)
constexpr int NOUT = T_B * T_N * 4 * NP1;   // 1,204,224 per output tensor

DEVI unsigned rotl(unsigned x, int d) { return (x << d) | (x >> (32 - d)); }

// JAX threefry, PARTITIONABLE mode (default since jax 0.4.30):
// per-element counter i (uint64 iota) -> block inputs (hi32(i), lo32(i));
// for size < 2^32 that is (0, i). 32-bit output = out0 ^ out1.
DEVI float gumbel_noise(unsigned idx) {
  unsigned x0 = 0u, x1 = idx;
  const unsigned k0 = 0u, k1 = 42u, k2 = 0x1BD11BDAu ^ 0u ^ 42u;
  x0 += k0; x1 += k1;
#define TF_R(rr) { x0 += x1; x1 = rotl(x1, rr); x1 ^= x0; }
  TF_R(13) TF_R(15) TF_R(26) TF_R(6)   x0 += k1; x1 += k2 + 1u;
  TF_R(17) TF_R(29) TF_R(16) TF_R(24)  x0 += k2; x1 += k0 + 2u;
  TF_R(13) TF_R(15) TF_R(26) TF_R(6)   x0 += k0; x1 += k1 + 3u;
  TF_R(17) TF_R(29) TF_R(16) TF_R(24)  x0 += k1; x1 += k2 + 4u;
  TF_R(13) TF_R(15) TF_R(26) TF_R(6)   x0 += k2; x1 += k0 + 5u;
#undef TF_R
  const unsigned bits = x0 ^ x1;
  float u = __uint_as_float((bits >> 9) | 0x3f800000u) - 1.0f;  // [0,1)
  u = fmaxf(u, 0.0f);
  const float ex = -log1pf(-u);   // exponential sample
  return -logf(ex);               // gumbel
}

#define ACC4(ACC, FA, MA, MB, MC, MD)                                   \
  ACC[0] += FA.x * MA.x + FA.y * MB.x + FA.z * MC.x + FA.w * MD.x;      \
  ACC[1] += FA.x * MA.y + FA.y * MB.y + FA.z * MC.y + FA.w * MD.y;      \
  ACC[2] += FA.x * MA.z + FA.y * MB.z + FA.z * MC.z + FA.w * MD.z;      \
  ACC[3] += FA.x * MA.w + FA.y * MB.w + FA.z * MC.w + FA.w * MD.w;

}  // namespace

// One block per (batch, target). Phases:
//  0: stage attn_mask, compute mask_ped, build feat[49][96] in LDS
//  1: E = LayerNorm(feat @ W_embed + b) -> LDS [49][128]
//  2: qkv = E @ W_qkv + b, three passes (K, V, Q), one named accumulator each
//  3: per-head wave: scores/softmax/PV/gating in registers, masked em
//     softmax, threefry gumbel, sampled softmax. Writes both outputs.
// LDS arena = 18816 floats (75,264 B) + W1t etc = 79,816 B -> 2 blocks/CU.
//
// waves_per_eu(2,2): LDS caps us at 2 blocks/CU (= 2 waves/EU) no matter
// what, so let the register allocator use the full 256-VGPR budget for that
// occupancy. With the default heuristic (R2/R3) it capped at 128 VGPRs and
// demoted phase-3 arrays (qreg[32]+S[49]+A2r[32] + unroll temps) to scratch:
// 14 GB/dispatch of HBM spill traffic, latency-bound at 6 ms.
__global__ __attribute__((amdgpu_flat_work_group_size(256, 256),
                          amdgpu_waves_per_eu(2, 2)))
void edge_selector_kernel(
    const float* __restrict__ x, const float* __restrict__ A,
    const float* __restrict__ amask, const float* __restrict__ Wemb,
    const float* __restrict__ bemb, const float* __restrict__ gamma_,
    const float* __restrict__ beta_, const float* __restrict__ Wqkv,
    const float* __restrict__ bqkv, const float* __restrict__ W1g,
    const float* __restrict__ b1g, const float* __restrict__ W2g,
    const float* __restrict__ b2g, float* __restrict__ out) {
  __shared__ __align__(16) float F[18816];
  __shared__ __align__(16) float sW1t[32 * 32];  // W1 transposed: [f][e]
  __shared__ float sM[NP1];
  __shared__ float sB1[32];
  __shared__ float sW2s[32];
  __shared__ float sB2;

  float* const sE    = F;             // [49][128]  (phases 1-2)
  float* const sFeat = F + 6272;      // [49][96]   (phases 0-1)
  float* const sAM   = F + 10976;     // [48][48]   (phase 0)
  float* const sMp   = F + 13280;     // [48]       (phase 0)
  float* const sQT   = F;             // [4][32][49] (phase 3, over sE)
  float* const sK    = F + 6272;      // [4][49][32] (phase 3, over sFeat/sAM)
  float* const sV    = F + 12544;     // [4][49][32] (phase 3)

  const int t  = threadIdx.x;
  const int tg = blockIdx.x;
  const int bb = blockIdx.y;

  // ---------------- phase 0a: stage masks & small weights ----------------
  for (int idx = t; idx < 48 * 48; idx += 256) sAM[idx] = amask[bb * 2304 + idx];
  for (int idx = t; idx < 1024; idx += 256) {
    const int e = idx >> 5, f = idx & 31;
    sW1t[f * 32 + e] = W1g[idx];
  }
  if (t < 32) { sB1[t] = b1g[t]; sW2s[t] = W2g[t]; }
  if (t == 0) sB2 = b2g[0];
  __syncthreads();
  if (t < 48) {
    float s = 0.f;
    for (int j = 0; j < 48; ++j) s += sAM[t * 48 + j];
    sMp[t] = (s > 0.f) ? 1.f : 0.f;
    sM[t] = sAM[tg * 48 + t];
  }
  if (t == 0) sM[48] = 1.f;   // ghost column always attendable
  __syncthreads();

  // ---------------- phase 0b: feat = [xn[nb], x[tg], A'[nb,tg]] ----------
  {
    const float mt = sMp[tg];
    for (int idx = t; idx < NP1 * 32; idx += 256) {
      const int nb = idx >> 5, e = idx & 31;
      sFeat[nb * 96 + 32 + e] = x[(bb * 48 + tg) * 32 + e] * mt;
      float xv = 0.f, av = 0.f;
      if (nb < 48) {
        xv = x[(bb * 48 + nb) * 32 + e] * sMp[nb];
        av = A[(((bb * 48 + nb) * 48) + tg) * 32 + e] * sAM[tg * 48 + nb];
      }
      sFeat[nb * 96 + e]      = xv;
      sFeat[nb * 96 + 64 + e] = av;
    }
  }
  __syncthreads();

  const int dq   = t & 31;                 // output column quad (d = dq*4)
  const int nbq  = t >> 5;                 // row group
  const int nrow = (nbq == 0) ? 7 : 6;
  int nbr[7];
#pragma unroll
  for (int r = 0; r < 7; ++r) nbr[r] = (r == 6) ? 48 : (nbq + 8 * r);

  // ---------------- phase 1: E = LN(feat @ Wemb + bemb) ------------------
  {
    float acc[7][4];
#pragma unroll
    for (int r = 0; r < 7; ++r)
#pragma unroll
      for (int c = 0; c < 4; ++c) acc[r][c] = 0.f;

    for (int kc = 0; kc < 96; kc += 8) {
      float4 w[8];
#pragma unroll
      for (int kk = 0; kk < 8; ++kk)
        w[kk] = *(const float4*)&Wemb[(kc + kk) * 128 + dq * 4];
#pragma unroll
      for (int r = 0; r < 7; ++r)
        if (r < nrow) {
          const float* fr = &sFeat[nbr[r] * 96 + kc];
          const float4 fa = *(const float4*)fr;
          const float4 fb = *(const float4*)(fr + 4);
          ACC4(acc[r], fa, w[0], w[1], w[2], w[3]);
          ACC4(acc[r], fb, w[4], w[5], w[6], w[7]);
        }
    }
    const float4 be = *(const float4*)&bemb[dq * 4];
    const float4 gm = *(const float4*)&gamma_[dq * 4];
    const float4 bt = *(const float4*)&beta_[dq * 4];
#pragma unroll
    for (int r = 0; r < 7; ++r)
      if (r < nrow) {
        const float e0 = acc[r][0] + be.x, e1 = acc[r][1] + be.y;
        const float e2 = acc[r][2] + be.z, e3 = acc[r][3] + be.w;
        float s  = e0 + e1 + e2 + e3;
        float qs = e0 * e0 + e1 * e1 + e2 * e2 + e3 * e3;
#pragma unroll
        for (int md = 16; md; md >>= 1) {
          s  += __shfl_xor(s, md, 32);
          qs += __shfl_xor(qs, md, 32);
        }
        const float mu  = s * (1.0f / 128.0f);
        const float var = qs * (1.0f / 128.0f) - mu * mu;
        const float rs  = 1.0f / sqrtf(var + 1e-5f);
        float4 o;
        o.x = (e0 - mu) * rs * gm.x + bt.x;
        o.y = (e1 - mu) * rs * gm.y + bt.y;
        o.z = (e2 - mu) * rs * gm.z + bt.z;
        o.w = (e3 - mu) * rs * gm.w + bt.w;
        *(float4*)&sE[nbr[r] * 128 + dq * 4] = o;
      }
  }
  __syncthreads();

  // ---------------- phase 2: qkv = E @ Wqkv + b, three passes ------------
  const int h  = dq >> 3;
  const int e0c = (dq & 7) * 4;

  // --- K pass: store to sK (over dead sFeat/sAM) ---
  {
    float acc[7][4];
#pragma unroll
    for (int r = 0; r < 7; ++r)
#pragma unroll
      for (int c = 0; c < 4; ++c) acc[r][c] = 0.f;
    for (int kc = 0; kc < 128; kc += 4) {
      float4 ef[7];
#pragma unroll
      for (int r = 0; r < 7; ++r)
        if (r < nrow) ef[r] = *(const float4*)&sE[nbr[r] * 128 + kc];
      const float* wp = &Wqkv[kc * 384 + 128 + dq * 4];
      const float4 w0 = *(const float4*)wp;
      const float4 w1 = *(const float4*)(wp + 384);
      const float4 w2 = *(const float4*)(wp + 768);
      const float4 w3 = *(const float4*)(wp + 1152);
#pragma unroll
      for (int r = 0; r < 7; ++r)
        if (r < nrow) { const float4 f = ef[r]; ACC4(acc[r], f, w0, w1, w2, w3); }
    }
    const float4 bkv = *(const float4*)&bqkv[128 + dq * 4];
#pragma unroll
    for (int r = 0; r < 7; ++r)
      if (r < nrow) {
        float4 ko;
        ko.x = acc[r][0] + bkv.x; ko.y = acc[r][1] + bkv.y;
        ko.z = acc[r][2] + bkv.z; ko.w = acc[r][3] + bkv.w;
        *(float4*)&sK[(h * 49 + nbr[r]) * 32 + e0c] = ko;
      }
  }

  // --- V pass: store to sV ---
  {
    float acc[7][4];
#pragma unroll
    for (int r = 0; r < 7; ++r)
#pragma unroll
      for (int c = 0; c < 4; ++c) acc[r][c] = 0.f;
    for (int kc = 0; kc < 128; kc += 4) {
      float4 ef[7];
#pragma unroll
      for (int r = 0; r < 7; ++r)
        if (r < nrow) ef[r] = *(const float4*)&sE[nbr[r] * 128 + kc];
      const float* wp = &Wqkv[kc * 384 + 256 + dq * 4];
      const float4 w0 = *(const float4*)wp;
      const float4 w1 = *(const float4*)(wp + 384);
      const float4 w2 = *(const float4*)(wp + 768);
      const float4 w3 = *(const float4*)(wp + 1152);
#pragma unroll
      for (int r = 0; r < 7; ++r)
        if (r < nrow) { const float4 f = ef[r]; ACC4(acc[r], f, w0, w1, w2, w3); }
    }
    const float4 bvv = *(const float4*)&bqkv[256 + dq * 4];
#pragma unroll
    for (int r = 0; r < 7; ++r)
      if (r < nrow) {
        float4 vo;
        vo.x = acc[r][0] + bvv.x; vo.y = acc[r][1] + bvv.y;
        vo.z = acc[r][2] + bvv.z; vo.w = acc[r][3] + bvv.w;
        *(float4*)&sV[(h * 49 + nbr[r]) * 32 + e0c] = vo;
      }
  }

  // --- Q pass: accumulate in regs, barrier, then overwrite sE with qT ---
  {
    float acc[7][4];
#pragma unroll
    for (int r = 0; r < 7; ++r)
#pragma unroll
      for (int c = 0; c < 4; ++c) acc[r][c] = 0.f;
    for (int kc = 0; kc < 128; kc += 4) {
      float4 ef[7];
#pragma unroll
      for (int r = 0; r < 7; ++r)
        if (r < nrow) ef[r] = *(const float4*)&sE[nbr[r] * 128 + kc];
      const float* wp = &Wqkv[kc * 384 + dq * 4];
      const float4 w0 = *(const float4*)wp;
      const float4 w1 = *(const float4*)(wp + 384);
      const float4 w2 = *(const float4*)(wp + 768);
      const float4 w3 = *(const float4*)(wp + 1152);
#pragma unroll
      for (int r = 0; r < 7; ++r)
        if (r < nrow) { const float4 f = ef[r]; ACC4(acc[r], f, w0, w1, w2, w3); }
    }
    __syncthreads();  // everyone done reading sE -> safe to overwrite with qT
    const float4 bqv = *(const float4*)&bqkv[dq * 4];
    const float SC = 0.17677669529663687f;  // 1/sqrt(32)
#pragma unroll
    for (int r = 0; r < 7; ++r)
      if (r < nrow) {
        const int nb = nbr[r];
        sQT[(h * 32 + e0c + 0) * 49 + nb] = (acc[r][0] + bqv.x) * SC;
        sQT[(h * 32 + e0c + 1) * 49 + nb] = (acc[r][1] + bqv.y) * SC;
        sQT[(h * 32 + e0c + 2) * 49 + nb] = (acc[r][2] + bqv.z) * SC;
        sQT[(h * 32 + e0c + 3) * 49 + nb] = (acc[r][3] + bqv.w) * SC;
      }
  }
  __syncthreads();

  // ---------------- phase 3: attention + gating + em + sampled -----------
  {
    const int wh   = t >> 6;       // head (one wave per head)
    const int lane = t & 63;
    const bool act = lane < NP1;
    const int i    = act ? lane : 0;

    float qreg[32];
#pragma unroll
    for (int e = 0; e < 32; ++e) qreg[e] = sQT[(wh * 32 + e) * 49 + i];
    const float mi = act ? sM[i] : 0.f;
    const bool mj = act ? (sM[lane] > 0.f) : false;
    const unsigned long long mbits = __ballot(mj);

    float S[NP1];
#pragma unroll
    for (int j = 0; j < NP1; ++j) {
      const float4* kr = (const float4*)&sK[(wh * 49 + j) * 32];
      float a = 0.f;
#pragma unroll
      for (int eq = 0; eq < 8; ++eq) {
        const float4 k4 = kr[eq];
        a += qreg[eq * 4 + 0] * k4.x + qreg[eq * 4 + 1] * k4.y +
             qreg[eq * 4 + 2] * k4.z + qreg[eq * 4 + 3] * k4.w;
      }
      S[j] = a;
    }
    const bool rowok = mi > 0.f;
#pragma unroll
    for (int j = 0; j < NP1; ++j) {
      const bool ok = rowok && ((mbits >> j) & 1ull);
      S[j] = ok ? S[j] : -1e9f;
    }
    float mx = S[0];
#pragma unroll
    for (int j = 1; j < NP1; ++j) mx = fmaxf(mx, S[j]);
    float ssum = 0.f;
#pragma unroll
    for (int j = 0; j < NP1; ++j) { S[j] = expf(S[j] - mx); ssum += S[j]; }
    const float sinv = 1.0f / ssum;
#pragma unroll
    for (int j = 0; j < NP1; ++j) S[j] *= sinv;

    float A2r[32];
#pragma unroll
    for (int e = 0; e < 32; ++e) A2r[e] = 0.f;
#pragma unroll
    for (int j = 0; j < NP1; ++j) {
      const float4* vr = (const float4*)&sV[(wh * 49 + j) * 32];
#pragma unroll
      for (int eq = 0; eq < 8; ++eq) {
        const float4 v4 = vr[eq];
        A2r[eq * 4 + 0] += S[j] * v4.x;
        A2r[eq * 4 + 1] += S[j] * v4.y;
        A2r[eq * 4 + 2] += S[j] * v4.z;
        A2r[eq * 4 + 3] += S[j] * v4.w;
      }
    }

    // gating MLP: s2 = W2 . relu(W1^T A2 + b1) + b2
    float s2 = sB2;
#pragma unroll
    for (int f = 0; f < 32; ++f) {
      const float4* wr = (const float4*)&sW1t[f * 32];
      float a = sB1[f];
#pragma unroll
      for (int eq = 0; eq < 8; ++eq) {
        const float4 w4 = wr[eq];
        a += A2r[eq * 4 + 0] * w4.x + A2r[eq * 4 + 1] * w4.y +
             A2r[eq * 4 + 2] * w4.z + A2r[eq * 4 + 3] * w4.w;
      }
      s2 += fmaxf(a, 0.f) * sW2s[f];
    }

    // em = normalize(softmax_i(s2) * m)
    const float v0 = act ? s2 : -1e30f;
    float mx2 = v0;
#pragma unroll
    for (int md = 32; md; md >>= 1) mx2 = fmaxf(mx2, __shfl_xor(mx2, md));
    float p = act ? expf(v0 - mx2) : 0.f;
    float ps = p;
#pragma unroll
    for (int md = 32; md; md >>= 1) ps += __shfl_xor(ps, md);
    float em = (p / ps) * mi;
    float es = em;
#pragma unroll
    for (int md = 32; md; md >>= 1) es += __shfl_xor(es, md);
    em = em / (es + 1e-10f);

    const int base = ((bb * 48 + tg) * 4 + wh) * 49;
    if (act) out[base + lane] = em;

    // sampled = softmax(log(em + 1e-10) + gumbel)
    const float lg = logf(em + 1e-10f);
    const float gn = gumbel_noise((unsigned)(base + lane));
    const float z = act ? (lg + gn) : -1e30f;
    float mx3 = z;
#pragma unroll
    for (int md = 32; md; md >>= 1) mx3 = fmaxf(mx3, __shfl_xor(mx3, md));
    float p3 = act ? expf(z - mx3) : 0.f;
    float ps3 = p3;
#pragma unroll
    for (int md = 32; md; md >>= 1) ps3 += __shfl_xor(ps3, md);
    if (act) out[NOUT + base + lane] = p3 / ps3;
  }
}

extern "C" void kernel_launch(void* const* d_in, const int* in_sizes, int n_in,
                              void* d_out, int out_size, void* d_ws, size_t ws_size,
                              hipStream_t stream) {
  (void)in_sizes; (void)n_in; (void)out_size; (void)d_ws; (void)ws_size;
  const float* x    = (const float*)d_in[0];
  const float* A    = (const float*)d_in[1];
  const float* am   = (const float*)d_in[2];
  const float* Wemb = (const float*)d_in[3];
  const float* bemb = (const float*)d_in[4];
  const float* gm   = (const float*)d_in[5];
  const float* bt   = (const float*)d_in[6];
  const float* Wqkv = (const float*)d_in[7];
  const float* bqkv = (const float*)d_in[8];
  const float* W1   = (const float*)d_in[9];
  const float* b1   = (const float*)d_in[10];
  const float* W2   = (const float*)d_in[11];
  const float* b2   = (const float*)d_in[12];
  dim3 grid(T_N, T_B);
  edge_selector_kernel<<<grid, 256, 0, stream>>>(
      x, A, am, Wemb, bemb, gm, bt, Wqkv, bqkv, W1, b1, W2, b2, (float*)d_out);
}

// Round 5
// 1217.827 us; speedup vs baseline: 5.0064x; 5.0043x over previous
//
#include <hip/hip_runtime.h>
#include <cstdint>
#include <cstddef>

#define DEVI __device__ __forceinline__

namespace {

constexpr int T_B = 128;
constexpr int T_N = 48;
constexpr int NP1 = 49;          // n+1 (ghost node)
constexpr int NOUT = T_B * T_N * 4 * NP1;   // 1,204,224 per output tensor

DEVI unsigned rotl(unsigned x, int d) { return (x << d) | (x >> (32 - d)); }

// JAX threefry, PARTITIONABLE mode (default since jax 0.4.30):
// per-element counter i (uint64 iota) -> block inputs (hi32(i), lo32(i));
// for size < 2^32 that is (0, i). 32-bit output = out0 ^ out1.
DEVI float gumbel_noise(unsigned idx) {
  unsigned x0 = 0u, x1 = idx;
  const unsigned k0 = 0u, k1 = 42u, k2 = 0x1BD11BDAu ^ 0u ^ 42u;
  x0 += k0; x1 += k1;
#define TF_R(rr) { x0 += x1; x1 = rotl(x1, rr); x1 ^= x0; }
  TF_R(13) TF_R(15) TF_R(26) TF_R(6)   x0 += k1; x1 += k2 + 1u;
  TF_R(17) TF_R(29) TF_R(16) TF_R(24)  x0 += k2; x1 += k0 + 2u;
  TF_R(13) TF_R(15) TF_R(26) TF_R(6)   x0 += k0; x1 += k1 + 3u;
  TF_R(17) TF_R(29) TF_R(16) TF_R(24)  x0 += k1; x1 += k2 + 4u;
  TF_R(13) TF_R(15) TF_R(26) TF_R(6)   x0 += k2; x1 += k0 + 5u;
#undef TF_R
  const unsigned bits = x0 ^ x1;
  float u = __uint_as_float((bits >> 9) | 0x3f800000u) - 1.0f;  // [0,1)
  u = fmaxf(u, 0.0f);
  const float ex = -log1pf(-u);   // exponential sample
  return -logf(ex);               // gumbel
}

#define ACC4(ACC, FA, MA, MB, MC, MD)                                   \
  ACC[0] += FA.x * MA.x + FA.y * MB.x + FA.z * MC.x + FA.w * MD.x;      \
  ACC[1] += FA.x * MA.y + FA.y * MB.y + FA.z * MC.y + FA.w * MD.y;      \
  ACC[2] += FA.x * MA.z + FA.y * MB.z + FA.z * MC.z + FA.w * MD.z;      \
  ACC[3] += FA.x * MA.w + FA.y * MB.w + FA.z * MC.w + FA.w * MD.w;

#define DOT4(Aa, Bb) ((Aa).x * (Bb).x + (Aa).y * (Bb).y + (Aa).z * (Bb).z + (Aa).w * (Bb).w)

// acc = acc*al + p*v, per component (no float4 operator dependence)
#define OFMA4(Aa, AL, P, Vv)                       \
  (Aa).x = (Aa).x * (AL) + (P) * (Vv).x;           \
  (Aa).y = (Aa).y * (AL) + (P) * (Vv).y;           \
  (Aa).z = (Aa).z * (AL) + (P) * (Vv).z;           \
  (Aa).w = (Aa).w * (AL) + (P) * (Vv).w;

}  // namespace

// One block per (batch, target). Phases:
//  0: stage attn_mask, compute mask_ped, build feat[49][96] in LDS
//  1: E = LayerNorm(feat @ W_embed + b) -> LDS [49][128]
//  2: qkv = E @ W_qkv + b, three passes (K, V, Q), one named accumulator each
//  3: per-head wave, lane = attention row. ONLINE softmax + PV with ZERO
//     per-lane arrays: q and the PV accumulator are 8 named float4s each,
//     the 49-wide score row is never materialized (running max m, sum l,
//     rescale by alpha). R2-R4 evidence: S[49]/A2r[32]/qreg[32] were never
//     promoted out of scratch (VGPR_Count pinned at 128 regardless of
//     waves_per_eu; WRITE_SIZE 9.3 GB = 49x32x4B/thread = A2r RMW traffic).
//     Named scalars/float4s with static access cannot be demoted.
// LDS arena = 18816 floats (75,264 B) + W1t etc = 79,816 B -> 2 blocks/CU.
__global__ __launch_bounds__(256, 2) void edge_selector_kernel(
    const float* __restrict__ x, const float* __restrict__ A,
    const float* __restrict__ amask, const float* __restrict__ Wemb,
    const float* __restrict__ bemb, const float* __restrict__ gamma_,
    const float* __restrict__ beta_, const float* __restrict__ Wqkv,
    const float* __restrict__ bqkv, const float* __restrict__ W1g,
    const float* __restrict__ b1g, const float* __restrict__ W2g,
    const float* __restrict__ b2g, float* __restrict__ out) {
  __shared__ __align__(16) float F[18816];
  __shared__ __align__(16) float sW1t[32 * 32];  // W1 transposed: [f][e]
  __shared__ float sM[NP1];
  __shared__ float sB1[32];
  __shared__ float sW2s[32];
  __shared__ float sB2;

  float* const sE    = F;             // [49][128]  (phases 1-2)
  float* const sFeat = F + 6272;      // [49][96]   (phases 0-1)
  float* const sAM   = F + 10976;     // [48][48]   (phase 0)
  float* const sMp   = F + 13280;     // [48]       (phase 0)
  float* const sQT   = F;             // [4][32][49] (phase 3, over sE)
  float* const sK    = F + 6272;      // [4][49][32] (phase 3, over sFeat/sAM)
  float* const sV    = F + 12544;     // [4][49][32] (phase 3)

  const int t  = threadIdx.x;
  const int tg = blockIdx.x;
  const int bb = blockIdx.y;

  // ---------------- phase 0a: stage masks & small weights ----------------
  for (int idx = t; idx < 48 * 48; idx += 256) sAM[idx] = amask[bb * 2304 + idx];
  for (int idx = t; idx < 1024; idx += 256) {
    const int e = idx >> 5, f = idx & 31;
    sW1t[f * 32 + e] = W1g[idx];
  }
  if (t < 32) { sB1[t] = b1g[t]; sW2s[t] = W2g[t]; }
  if (t == 0) sB2 = b2g[0];
  __syncthreads();
  if (t < 48) {
    float s = 0.f;
    for (int j = 0; j < 48; ++j) s += sAM[t * 48 + j];
    sMp[t] = (s > 0.f) ? 1.f : 0.f;
    sM[t] = sAM[tg * 48 + t];
  }
  if (t == 0) sM[48] = 1.f;   // ghost column always attendable
  __syncthreads();

  // ---------------- phase 0b: feat = [xn[nb], x[tg], A'[nb,tg]] ----------
  {
    const float mt = sMp[tg];
    for (int idx = t; idx < NP1 * 32; idx += 256) {
      const int nb = idx >> 5, e = idx & 31;
      sFeat[nb * 96 + 32 + e] = x[(bb * 48 + tg) * 32 + e] * mt;
      float xv = 0.f, av = 0.f;
      if (nb < 48) {
        xv = x[(bb * 48 + nb) * 32 + e] * sMp[nb];
        av = A[(((bb * 48 + nb) * 48) + tg) * 32 + e] * sAM[tg * 48 + nb];
      }
      sFeat[nb * 96 + e]      = xv;
      sFeat[nb * 96 + 64 + e] = av;
    }
  }
  __syncthreads();

  const int dq   = t & 31;                 // output column quad (d = dq*4)
  const int nbq  = t >> 5;                 // row group
  const int nrow = (nbq == 0) ? 7 : 6;
  int nbr[7];
#pragma unroll
  for (int r = 0; r < 7; ++r) nbr[r] = (r == 6) ? 48 : (nbq + 8 * r);

  // ---------------- phase 1: E = LN(feat @ Wemb + bemb) ------------------
  {
    float acc[7][4];
#pragma unroll
    for (int r = 0; r < 7; ++r)
#pragma unroll
      for (int c = 0; c < 4; ++c) acc[r][c] = 0.f;

    for (int kc = 0; kc < 96; kc += 8) {
      float4 w[8];
#pragma unroll
      for (int kk = 0; kk < 8; ++kk)
        w[kk] = *(const float4*)&Wemb[(kc + kk) * 128 + dq * 4];
#pragma unroll
      for (int r = 0; r < 7; ++r)
        if (r < nrow) {
          const float* fr = &sFeat[nbr[r] * 96 + kc];
          const float4 fa = *(const float4*)fr;
          const float4 fb = *(const float4*)(fr + 4);
          ACC4(acc[r], fa, w[0], w[1], w[2], w[3]);
          ACC4(acc[r], fb, w[4], w[5], w[6], w[7]);
        }
    }
    const float4 be = *(const float4*)&bemb[dq * 4];
    const float4 gm = *(const float4*)&gamma_[dq * 4];
    const float4 bt = *(const float4*)&beta_[dq * 4];
#pragma unroll
    for (int r = 0; r < 7; ++r)
      if (r < nrow) {
        const float e0 = acc[r][0] + be.x, e1 = acc[r][1] + be.y;
        const float e2 = acc[r][2] + be.z, e3 = acc[r][3] + be.w;
        float s  = e0 + e1 + e2 + e3;
        float qs = e0 * e0 + e1 * e1 + e2 * e2 + e3 * e3;
#pragma unroll
        for (int md = 16; md; md >>= 1) {
          s  += __shfl_xor(s, md, 32);
          qs += __shfl_xor(qs, md, 32);
        }
        const float mu  = s * (1.0f / 128.0f);
        const float var = qs * (1.0f / 128.0f) - mu * mu;
        const float rs  = 1.0f / sqrtf(var + 1e-5f);
        float4 o;
        o.x = (e0 - mu) * rs * gm.x + bt.x;
        o.y = (e1 - mu) * rs * gm.y + bt.y;
        o.z = (e2 - mu) * rs * gm.z + bt.z;
        o.w = (e3 - mu) * rs * gm.w + bt.w;
        *(float4*)&sE[nbr[r] * 128 + dq * 4] = o;
      }
  }
  __syncthreads();

  // ---------------- phase 2: qkv = E @ Wqkv + b, three passes ------------
  const int h  = dq >> 3;
  const int e0c = (dq & 7) * 4;

  // --- K pass: store to sK (over dead sFeat/sAM) ---
  {
    float acc[7][4];
#pragma unroll
    for (int r = 0; r < 7; ++r)
#pragma unroll
      for (int c = 0; c < 4; ++c) acc[r][c] = 0.f;
    for (int kc = 0; kc < 128; kc += 4) {
      float4 ef[7];
#pragma unroll
      for (int r = 0; r < 7; ++r)
        if (r < nrow) ef[r] = *(const float4*)&sE[nbr[r] * 128 + kc];
      const float* wp = &Wqkv[kc * 384 + 128 + dq * 4];
      const float4 w0 = *(const float4*)wp;
      const float4 w1 = *(const float4*)(wp + 384);
      const float4 w2 = *(const float4*)(wp + 768);
      const float4 w3 = *(const float4*)(wp + 1152);
#pragma unroll
      for (int r = 0; r < 7; ++r)
        if (r < nrow) { const float4 f = ef[r]; ACC4(acc[r], f, w0, w1, w2, w3); }
    }
    const float4 bkv = *(const float4*)&bqkv[128 + dq * 4];
#pragma unroll
    for (int r = 0; r < 7; ++r)
      if (r < nrow) {
        float4 ko;
        ko.x = acc[r][0] + bkv.x; ko.y = acc[r][1] + bkv.y;
        ko.z = acc[r][2] + bkv.z; ko.w = acc[r][3] + bkv.w;
        *(float4*)&sK[(h * 49 + nbr[r]) * 32 + e0c] = ko;
      }
  }

  // --- V pass: store to sV ---
  {
    float acc[7][4];
#pragma unroll
    for (int r = 0; r < 7; ++r)
#pragma unroll
      for (int c = 0; c < 4; ++c) acc[r][c] = 0.f;
    for (int kc = 0; kc < 128; kc += 4) {
      float4 ef[7];
#pragma unroll
      for (int r = 0; r < 7; ++r)
        if (r < nrow) ef[r] = *(const float4*)&sE[nbr[r] * 128 + kc];
      const float* wp = &Wqkv[kc * 384 + 256 + dq * 4];
      const float4 w0 = *(const float4*)wp;
      const float4 w1 = *(const float4*)(wp + 384);
      const float4 w2 = *(const float4*)(wp + 768);
      const float4 w3 = *(const float4*)(wp + 1152);
#pragma unroll
      for (int r = 0; r < 7; ++r)
        if (r < nrow) { const float4 f = ef[r]; ACC4(acc[r], f, w0, w1, w2, w3); }
    }
    const float4 bvv = *(const float4*)&bqkv[256 + dq * 4];
#pragma unroll
    for (int r = 0; r < 7; ++r)
      if (r < nrow) {
        float4 vo;
        vo.x = acc[r][0] + bvv.x; vo.y = acc[r][1] + bvv.y;
        vo.z = acc[r][2] + bvv.z; vo.w = acc[r][3] + bvv.w;
        *(float4*)&sV[(h * 49 + nbr[r]) * 32 + e0c] = vo;
      }
  }

  // --- Q pass: accumulate in regs, barrier, then overwrite sE with qT ---
  {
    float acc[7][4];
#pragma unroll
    for (int r = 0; r < 7; ++r)
#pragma unroll
      for (int c = 0; c < 4; ++c) acc[r][c] = 0.f;
    for (int kc = 0; kc < 128; kc += 4) {
      float4 ef[7];
#pragma unroll
      for (int r = 0; r < 7; ++r)
        if (r < nrow) ef[r] = *(const float4*)&sE[nbr[r] * 128 + kc];
      const float* wp = &Wqkv[kc * 384 + dq * 4];
      const float4 w0 = *(const float4*)wp;
      const float4 w1 = *(const float4*)(wp + 384);
      const float4 w2 = *(const float4*)(wp + 768);
      const float4 w3 = *(const float4*)(wp + 1152);
#pragma unroll
      for (int r = 0; r < 7; ++r)
        if (r < nrow) { const float4 f = ef[r]; ACC4(acc[r], f, w0, w1, w2, w3); }
    }
    __syncthreads();  // everyone done reading sE -> safe to overwrite with qT
    const float4 bqv = *(const float4*)&bqkv[dq * 4];
    const float SC = 0.17677669529663687f;  // 1/sqrt(32)
#pragma unroll
    for (int r = 0; r < 7; ++r)
      if (r < nrow) {
        const int nb = nbr[r];
        sQT[(h * 32 + e0c + 0) * 49 + nb] = (acc[r][0] + bqv.x) * SC;
        sQT[(h * 32 + e0c + 1) * 49 + nb] = (acc[r][1] + bqv.y) * SC;
        sQT[(h * 32 + e0c + 2) * 49 + nb] = (acc[r][2] + bqv.z) * SC;
        sQT[(h * 32 + e0c + 3) * 49 + nb] = (acc[r][3] + bqv.w) * SC;
      }
  }
  __syncthreads();

  // ---------------- phase 3: attention + gating + em + sampled -----------
  {
    const int wh   = t >> 6;       // head (one wave per head)
    const int lane = t & 63;
    const bool act = lane < NP1;
    const int i    = act ? lane : 0;

    // q row i of head wh from transposed qT (consecutive lanes ->
    // consecutive addresses, conflict-free). 8 NAMED float4s, no array.
    float4 q0, q1, q2, q3, q4, q5, q6, q7;
#define LDQ4(Q, E)                                 \
    Q.x = sQT[((wh * 32) + (E) + 0) * 49 + i];     \
    Q.y = sQT[((wh * 32) + (E) + 1) * 49 + i];     \
    Q.z = sQT[((wh * 32) + (E) + 2) * 49 + i];     \
    Q.w = sQT[((wh * 32) + (E) + 3) * 49 + i];
    LDQ4(q0, 0)  LDQ4(q1, 4)  LDQ4(q2, 8)  LDQ4(q3, 12)
    LDQ4(q4, 16) LDQ4(q5, 20) LDQ4(q6, 24) LDQ4(q7, 28)
#undef LDQ4

    const float mi = act ? sM[i] : 0.f;
    const bool mj = act ? (sM[lane] > 0.f) : false;
    const unsigned long long mbits = __ballot(mj);
    const bool rowok = mi > 0.f;

    // Online softmax + PV fused: running max m, running sum l, accumulator
    // rescaled by al = exp(m_old - m_new). Exactly equals softmax-then-PV:
    // masked j give p = exp(-1e9 - m) = 0; fully-masked rows never see a
    // real score, so every p = 1 -> uniform 1/49, matching the reference's
    // softmax over all -1e9.
    float m = -1e30f, l = 0.f;
    float4 a0, a1, a2, a3, a4, a5, a6, a7;
    a0 = a1 = a2 = a3 = a4 = a5 = a6 = a7 = make_float4(0.f, 0.f, 0.f, 0.f);

    for (int j = 0; j < NP1; ++j) {
      const float4* kr = (const float4*)&sK[(wh * 49 + j) * 32];
      const float4 k0 = kr[0], k1 = kr[1], k2 = kr[2], k3 = kr[3];
      const float4 k4 = kr[4], k5 = kr[5], k6 = kr[6], k7 = kr[7];
      float s = DOT4(q0, k0) + DOT4(q1, k1) + DOT4(q2, k2) + DOT4(q3, k3) +
                DOT4(q4, k4) + DOT4(q5, k5) + DOT4(q6, k6) + DOT4(q7, k7);
      const bool ok = rowok && ((mbits >> j) & 1ull);
      s = ok ? s : -1e9f;
      const float mnew = fmaxf(m, s);
      const float al = expf(m - mnew);
      const float p  = expf(s - mnew);
      m = mnew;
      l = l * al + p;
      const float4* vr = (const float4*)&sV[(wh * 49 + j) * 32];
      const float4 v0 = vr[0], v1 = vr[1], v2 = vr[2], v3 = vr[3];
      const float4 v4 = vr[4], v5 = vr[5], v6 = vr[6], v7 = vr[7];
      OFMA4(a0, al, p, v0) OFMA4(a1, al, p, v1)
      OFMA4(a2, al, p, v2) OFMA4(a3, al, p, v3)
      OFMA4(a4, al, p, v4) OFMA4(a5, al, p, v5)
      OFMA4(a6, al, p, v6) OFMA4(a7, al, p, v7)
    }
    {
      const float linv = 1.0f / l;   // l >= 1 always (ghost col or uniform)
      a0.x *= linv; a0.y *= linv; a0.z *= linv; a0.w *= linv;
      a1.x *= linv; a1.y *= linv; a1.z *= linv; a1.w *= linv;
      a2.x *= linv; a2.y *= linv; a2.z *= linv; a2.w *= linv;
      a3.x *= linv; a3.y *= linv; a3.z *= linv; a3.w *= linv;
      a4.x *= linv; a4.y *= linv; a4.z *= linv; a4.w *= linv;
      a5.x *= linv; a5.y *= linv; a5.z *= linv; a5.w *= linv;
      a6.x *= linv; a6.y *= linv; a6.z *= linv; a6.w *= linv;
      a7.x *= linv; a7.y *= linv; a7.z *= linv; a7.w *= linv;
    }

    // gating MLP: s2 = W2 . relu(W1^T A2 + b1) + b2  (scalar state only)
    float s2 = sB2;
    for (int f = 0; f < 32; ++f) {
      const float4* wr = (const float4*)&sW1t[f * 32];
      const float4 w0 = wr[0], w1 = wr[1], w2 = wr[2], w3 = wr[3];
      const float4 w4 = wr[4], w5 = wr[5], w6 = wr[6], w7 = wr[7];
      float g = sB1[f] +
          DOT4(a0, w0) + DOT4(a1, w1) + DOT4(a2, w2) + DOT4(a3, w3) +
          DOT4(a4, w4) + DOT4(a5, w5) + DOT4(a6, w6) + DOT4(a7, w7);
      s2 += fmaxf(g, 0.f) * sW2s[f];
    }

    // em = normalize(softmax_i(s2) * m)
    const float v0s = act ? s2 : -1e30f;
    float mx2 = v0s;
#pragma unroll
    for (int md = 32; md; md >>= 1) mx2 = fmaxf(mx2, __shfl_xor(mx2, md));
    float p = act ? expf(v0s - mx2) : 0.f;
    float ps = p;
#pragma unroll
    for (int md = 32; md; md >>= 1) ps += __shfl_xor(ps, md);
    float em = (p / ps) * mi;
    float es = em;
#pragma unroll
    for (int md = 32; md; md >>= 1) es += __shfl_xor(es, md);
    em = em / (es + 1e-10f);

    const int base = ((bb * 48 + tg) * 4 + wh) * 49;
    if (act) out[base + lane] = em;

    // sampled = softmax(log(em + 1e-10) + gumbel)
    const float lg = logf(em + 1e-10f);
    const float gn = gumbel_noise((unsigned)(base + lane));
    const float z = act ? (lg + gn) : -1e30f;
    float mx3 = z;
#pragma unroll
    for (int md = 32; md; md >>= 1) mx3 = fmaxf(mx3, __shfl_xor(mx3, md));
    float p3 = act ? expf(z - mx3) : 0.f;
    float ps3 = p3;
#pragma unroll
    for (int md = 32; md; md >>= 1) ps3 += __shfl_xor(ps3, md);
    if (act) out[NOUT + base + lane] = p3 / ps3;
  }
}

extern "C" void kernel_launch(void* const* d_in, const int* in_sizes, int n_in,
                              void* d_out, int out_size, void* d_ws, size_t ws_size,
                              hipStream_t stream) {
  (void)in_sizes; (void)n_in; (void)out_size; (void)d_ws; (void)ws_size;
  const float* x    = (const float*)d_in[0];
  const float* A    = (const float*)d_in[1];
  const float* am   = (const float*)d_in[2];
  const float* Wemb = (const float*)d_in[3];
  const float* bemb = (const float*)d_in[4];
  const float* gm   = (const float*)d_in[5];
  const float* bt   = (const float*)d_in[6];
  const float* Wqkv = (const float*)d_in[7];
  const float* bqkv = (const float*)d_in[8];
  const float* W1   = (const float*)d_in[9];
  const float* b1   = (const float*)d_in[10];
  const float* W2   = (const float*)d_in[11];
  const float* b2   = (const float*)d_in[12];
  dim3 grid(T_N, T_B);
  edge_selector_kernel<<<grid, 256, 0, stream>>>(
      x, A, am, Wemb, bemb, gm, bt, Wqkv, bqkv, W1, b1, W2, b2, (float*)d_out);
}

// Round 6
// 834.258 us; speedup vs baseline: 7.3082x; 1.4598x over previous
//
#include <hip/hip_runtime.h>
#include <cstdint>
#include <cstddef>

#define DEVI __device__ __forceinline__

namespace {

constexpr int T_B = 128;
constexpr int T_N = 48;
constexpr int NP1 = 49;          // n+1 (ghost node)
constexpr int NOUT = T_B * T_N * 4 * NP1;   // 1,204,224 per output tensor

using short8 = __attribute__((ext_vector_type(8))) short;   // 8 bf16
using f32x4  = __attribute__((ext_vector_type(4))) float;

DEVI unsigned rotl(unsigned x, int d) { return (x << d) | (x >> (32 - d)); }

// JAX threefry, PARTITIONABLE mode: counter (0, i), output = x0 ^ x1.
DEVI float gumbel_noise(unsigned idx) {
  unsigned x0 = 0u, x1 = idx;
  const unsigned k0 = 0u, k1 = 42u, k2 = 0x1BD11BDAu ^ 0u ^ 42u;
  x0 += k0; x1 += k1;
#define TF_R(rr) { x0 += x1; x1 = rotl(x1, rr); x1 ^= x0; }
  TF_R(13) TF_R(15) TF_R(26) TF_R(6)   x0 += k1; x1 += k2 + 1u;
  TF_R(17) TF_R(29) TF_R(16) TF_R(24)  x0 += k2; x1 += k0 + 2u;
  TF_R(13) TF_R(15) TF_R(26) TF_R(6)   x0 += k0; x1 += k1 + 3u;
  TF_R(17) TF_R(29) TF_R(16) TF_R(24)  x0 += k1; x1 += k2 + 4u;
  TF_R(13) TF_R(15) TF_R(26) TF_R(6)   x0 += k2; x1 += k0 + 5u;
#undef TF_R
  const unsigned bits = x0 ^ x1;
  float u = __uint_as_float((bits >> 9) | 0x3f800000u) - 1.0f;
  u = fmaxf(u, 0.0f);
  const float ex = -log1pf(-u);
  return -logf(ex);
}

// fp32 -> bf16 round-to-nearest-even (values are finite/sane here)
DEVI unsigned short f2bf(float f) {
  const unsigned u = __float_as_uint(f);
  return (unsigned short)((u + 0x7fffu + ((u >> 16) & 1u)) >> 16);
}
DEVI float bf2f(unsigned short u) { return __uint_as_float(((unsigned)u) << 16); }

#define ACC4(ACC, FA, MA, MB, MC, MD)                                   \
  ACC[0] += FA.x * MA.x + FA.y * MB.x + FA.z * MC.x + FA.w * MD.x;      \
  ACC[1] += FA.x * MA.y + FA.y * MB.y + FA.z * MC.y + FA.w * MD.y;      \
  ACC[2] += FA.x * MA.z + FA.y * MB.z + FA.z * MC.z + FA.w * MD.z;      \
  ACC[3] += FA.x * MA.w + FA.y * MB.w + FA.z * MC.w + FA.w * MD.w;

#define DOT4(Aa, Bb) ((Aa).x * (Bb).x + (Aa).y * (Bb).y + (Aa).z * (Bb).z + (Aa).w * (Bb).w)

// PV accumulate from a bf16 pair-packed dword pair (bf16->f32 is a <<16)
#define OFMAU(Aa, AL, P, D0, D1)                                        \
  (Aa).x = (Aa).x * (AL) + (P) * __uint_as_float((D0) << 16);           \
  (Aa).y = (Aa).y * (AL) + (P) * __uint_as_float((D0) & 0xffff0000u);   \
  (Aa).z = (Aa).z * (AL) + (P) * __uint_as_float((D1) << 16);           \
  (Aa).w = (Aa).w * (AL) + (P) * __uint_as_float((D1) & 0xffff0000u);

}  // namespace

// Transposed bf16 hi/lo copy of W_qkv: g_Wt[n*128+k] = hi(W[k][n]),
// g_Wt[49152 + n*128+k] = lo. k-consecutive -> one b128 per B-fragment.
// L2-resident (192 KB). Device-global so no d_ws dependency.
__device__ __align__(16) unsigned short g_Wt[2 * 384 * 128];

__global__ void convert_wqkv_kernel(const float* __restrict__ Wqkv) {
  const int tid = blockIdx.x * 256 + threadIdx.x;
  if (tid < 49152) {
    const int n = tid >> 7, k = tid & 127;
    const float w = Wqkv[k * 384 + n];
    const unsigned short hi = f2bf(w);
    g_Wt[n * 128 + k] = hi;
    g_Wt[49152 + n * 128 + k] = f2bf(w - bf2f(hi));
  }
}

// One block per (batch, target).
//  0: masks, feat[49][96] (fp32), zero E pad rows, stage small weights
//  1: E = LN(feat @ Wemb + b) -> bf16 hi/lo [64][128], XOR-swizzled
//  2: qkv = E @ Wqkv via MFMA 16x16x32_bf16, split hi/lo (3 mfma per tile
//     k-step -> fp32-grade accuracy). 4 waves x 6 N-tiles x 4 M-tiles.
//     K -> fp32 LDS (over dead feat/mask); Q (bf16, transposed) and V
//     (bf16) -> over dead E after a barrier.
//  3: per-head wave, online softmax + PV (named float4 state only — R5
//     lesson: runtime-indexed arrays go to scratch), gating MLP, masked
//     em softmax, threefry gumbel, sampled softmax.
// LDS arena 64,896 B + small arrays -> ~65.5 KB -> 2 blocks/CU.
__global__ __launch_bounds__(256, 2) void edge_selector_kernel(
    const float* __restrict__ x, const float* __restrict__ A,
    const float* __restrict__ amask, const float* __restrict__ Wemb,
    const float* __restrict__ bemb, const float* __restrict__ gamma_,
    const float* __restrict__ beta_, const float* __restrict__ Wqkv,
    const float* __restrict__ bqkv, const float* __restrict__ W1g,
    const float* __restrict__ b1g, const float* __restrict__ W2g,
    const float* __restrict__ b2g, float* __restrict__ out) {
  // Arena byte map:
  //    0..16384 : sEhi ushort[64][128] (swizzled) | ph3: sQTb us[4*32*49]=12544
  // 16384..32768: sElo ushort[64][128] (swizzled) | ph3: sVb at +12544, 12544 B
  // 32768..51584: sFeat float[49][96]             | ph2+: sKf float[4*49*32]=25088
  // 51584..60800: sAM float[48][48]               |   (sKf tail overlaps sAM)
  // 60800..64896: sW1t float[1024]
  __shared__ __align__(16) unsigned char ARENA[64896];
  __shared__ float sM[NP1];
  __shared__ float sMp[48];
  __shared__ float sB1[32];
  __shared__ float sW2s[32];
  __shared__ float sB2;

  unsigned short* const sQTb = (unsigned short*)(ARENA);
  unsigned short* const sVb  = (unsigned short*)(ARENA + 12544);
  float* const sFeat = (float*)(ARENA + 32768);
  float* const sAM   = (float*)(ARENA + 51584);
  float* const sKf   = (float*)(ARENA + 32768);
  float* const sW1t  = (float*)(ARENA + 60800);

  const int t  = threadIdx.x;
  const int tg = blockIdx.x;
  const int bb = blockIdx.y;

  // ---------------- phase 0a: masks, small weights, zero E pad ----------
  for (int idx = t; idx < 48 * 48; idx += 256) sAM[idx] = amask[bb * 2304 + idx];
  for (int idx = t; idx < 1024; idx += 256) {
    const int e = idx >> 5, f = idx & 31;
    sW1t[f * 32 + e] = W1g[idx];
  }
  {
    unsigned* zh = (unsigned*)(ARENA + 49 * 256);          // E_hi rows 49-63
    unsigned* zl = (unsigned*)(ARENA + 16384 + 49 * 256);  // E_lo rows 49-63
    for (int idx = t; idx < 960; idx += 256) { zh[idx] = 0u; zl[idx] = 0u; }
  }
  if (t < 32) { sB1[t] = b1g[t]; sW2s[t] = W2g[t]; }
  if (t == 0) sB2 = b2g[0];
  __syncthreads();
  if (t < 48) {
    float s = 0.f;
    for (int j = 0; j < 48; ++j) s += sAM[t * 48 + j];
    sMp[t] = (s > 0.f) ? 1.f : 0.f;
    sM[t] = sAM[tg * 48 + t];
  }
  if (t == 0) sM[48] = 1.f;
  __syncthreads();

  // ---------------- phase 0b: feat = [xn[nb], x[tg], A'[nb,tg]] ----------
  {
    const float mt_ = sMp[tg];
    for (int idx = t; idx < NP1 * 32; idx += 256) {
      const int nb = idx >> 5, e = idx & 31;
      sFeat[nb * 96 + 32 + e] = x[(bb * 48 + tg) * 32 + e] * mt_;
      float xv = 0.f, av = 0.f;
      if (nb < 48) {
        xv = x[(bb * 48 + nb) * 32 + e] * sMp[nb];
        av = A[(((bb * 48 + nb) * 48) + tg) * 32 + e] * sM[nb];
      }
      sFeat[nb * 96 + e]      = xv;
      sFeat[nb * 96 + 64 + e] = av;
    }
  }
  __syncthreads();

  const int dq   = t & 31;
  const int nbq  = t >> 5;
  const int nrow = (nbq == 0) ? 7 : 6;
  int nbr[7];
#pragma unroll
  for (int r = 0; r < 7; ++r) nbr[r] = (r == 6) ? 48 : (nbq + 8 * r);

  // ---------------- phase 1: E = LN(feat @ Wemb + b) -> bf16 hi/lo -------
  {
    float acc[7][4];
#pragma unroll
    for (int r = 0; r < 7; ++r)
#pragma unroll
      for (int c = 0; c < 4; ++c) acc[r][c] = 0.f;

    for (int kc = 0; kc < 96; kc += 8) {
      float4 w[8];
#pragma unroll
      for (int kk = 0; kk < 8; ++kk)
        w[kk] = *(const float4*)&Wemb[(kc + kk) * 128 + dq * 4];
#pragma unroll
      for (int r = 0; r < 7; ++r)
        if (r < nrow) {
          const float* fr = &sFeat[nbr[r] * 96 + kc];
          const float4 fa = *(const float4*)fr;
          const float4 fb = *(const float4*)(fr + 4);
          ACC4(acc[r], fa, w[0], w[1], w[2], w[3]);
          ACC4(acc[r], fb, w[4], w[5], w[6], w[7]);
        }
    }
    const float4 be = *(const float4*)&bemb[dq * 4];
    const float4 gm = *(const float4*)&gamma_[dq * 4];
    const float4 bt = *(const float4*)&beta_[dq * 4];
#pragma unroll
    for (int r = 0; r < 7; ++r)
      if (r < nrow) {
        const float e0 = acc[r][0] + be.x, e1 = acc[r][1] + be.y;
        const float e2 = acc[r][2] + be.z, e3 = acc[r][3] + be.w;
        float s  = e0 + e1 + e2 + e3;
        float qs = e0 * e0 + e1 * e1 + e2 * e2 + e3 * e3;
#pragma unroll
        for (int md = 16; md; md >>= 1) {
          s  += __shfl_xor(s, md, 32);
          qs += __shfl_xor(qs, md, 32);
        }
        const float mu  = s * (1.0f / 128.0f);
        const float var = qs * (1.0f / 128.0f) - mu * mu;
        const float rs  = 1.0f / sqrtf(var + 1e-5f);
        float4 o;
        o.x = (e0 - mu) * rs * gm.x + bt.x;
        o.y = (e1 - mu) * rs * gm.y + bt.y;
        o.z = (e2 - mu) * rs * gm.z + bt.z;
        o.w = (e3 - mu) * rs * gm.w + bt.w;
        // bf16 hi/lo, pair-packed, XOR-swizzled within the 64B k-step block
        // (bits 4-5 only, so MFMA b128 reads stay inside their k-step).
        const int row = nbr[r];
        const unsigned short h0 = f2bf(o.x), h1 = f2bf(o.y);
        const unsigned short h2 = f2bf(o.z), h3 = f2bf(o.w);
        uint2 hv, lv;
        hv.x = (unsigned)h0 | ((unsigned)h1 << 16);
        hv.y = (unsigned)h2 | ((unsigned)h3 << 16);
        lv.x = (unsigned)f2bf(o.x - bf2f(h0)) | ((unsigned)f2bf(o.y - bf2f(h1)) << 16);
        lv.y = (unsigned)f2bf(o.z - bf2f(h2)) | ((unsigned)f2bf(o.w - bf2f(h3)) << 16);
        const int off = (dq * 8) ^ ((row & 3) << 4);
        *(uint2*)(ARENA + row * 256 + off) = hv;
        *(uint2*)(ARENA + 16384 + row * 256 + off) = lv;
      }
  }
  __syncthreads();

  // ---------------- phase 2: qkv = E @ Wqkv via MFMA (split bf16) --------
  {
    const int w  = t >> 6;           // wave -> N-tiles {6w..6w+5}
    const int l  = t & 63;
    const int lm = l & 15, lg = l >> 4;
    const float SC = 0.17677669529663687f;  // 1/sqrt(32)

    f32x4 acc[4][6];
#pragma unroll
    for (int mt = 0; mt < 4; ++mt)
#pragma unroll
      for (int nt = 0; nt < 6; ++nt) acc[mt][nt] = (f32x4){0.f, 0.f, 0.f, 0.f};

#pragma unroll
    for (int ks = 0; ks < 4; ++ks) {
      short8 ah[4], alo[4];
#pragma unroll
      for (int mt = 0; mt < 4; ++mt) {
        const int row = mt * 16 + lm;             // A row = lane&15  [m89]
        const int off = (ks * 64 + lg * 16) ^ ((row & 3) << 4);
        ah[mt]  = *(const short8*)(ARENA + row * 256 + off);
        alo[mt] = *(const short8*)(ARENA + 16384 + row * 256 + off);
      }
#pragma unroll
      for (int nt = 0; nt < 6; ++nt) {
        const int kid = ((w * 6 + nt) * 16 + lm) * 128 + ks * 32 + lg * 8;
        const short8 bh = *(const short8*)&g_Wt[kid];
        const short8 bl = *(const short8*)&g_Wt[49152 + kid];
#pragma unroll
        for (int mt = 0; mt < 4; ++mt) {
          acc[mt][nt] = __builtin_amdgcn_mfma_f32_16x16x32_bf16(ah[mt],  bh, acc[mt][nt], 0, 0, 0);
          acc[mt][nt] = __builtin_amdgcn_mfma_f32_16x16x32_bf16(alo[mt], bh, acc[mt][nt], 0, 0, 0);
          acc[mt][nt] = __builtin_amdgcn_mfma_f32_16x16x32_bf16(ah[mt],  bl, acc[mt][nt], 0, 0, 0);
        }
      }
    }

    float bias[6];
#pragma unroll
    for (int nt = 0; nt < 6; ++nt) bias[nt] = bqkv[(w * 6 + nt) * 16 + lm];

    const int rb = lg * 4;   // C row = (lane>>4)*4 + r  [m89]
    // K columns (tiles 8-15) -> fp32 over dead feat/mask region, pre-barrier
#pragma unroll
    for (int nt = 0; nt < 6; ++nt) {
      const int ntg = w * 6 + nt;
      if (ntg >= 8 && ntg < 16) {
        const int cc = ntg * 16 + lm - 128;
        const int hh = cc >> 5, ee = cc & 31;
#pragma unroll
        for (int mt = 0; mt < 4; ++mt)
#pragma unroll
          for (int r = 0; r < 4; ++r) {
            const int nb = mt * 16 + rb + r;
            if (nb < NP1) sKf[(hh * 49 + nb) * 32 + ee] = acc[mt][nt][r] + bias[nt];
          }
      }
    }
    __syncthreads();   // all MFMA reads of E done -> safe to overwrite
    // Q (tiles 0-7): scaled bf16, transposed; V (tiles 16-23): bf16
#pragma unroll
    for (int nt = 0; nt < 6; ++nt) {
      const int ntg = w * 6 + nt;
      const int c = ntg * 16 + lm;
      if (ntg < 8) {
        const int hh = c >> 5, ee = c & 31;
#pragma unroll
        for (int mt = 0; mt < 4; ++mt)
#pragma unroll
          for (int r = 0; r < 4; ++r) {
            const int nb = mt * 16 + rb + r;
            if (nb < NP1)
              sQTb[(hh * 32 + ee) * 49 + nb] = f2bf((acc[mt][nt][r] + bias[nt]) * SC);
          }
      } else if (ntg >= 16) {
        const int cc = c - 256;
        const int hh = cc >> 5, ee = cc & 31;
#pragma unroll
        for (int mt = 0; mt < 4; ++mt)
#pragma unroll
          for (int r = 0; r < 4; ++r) {
            const int nb = mt * 16 + rb + r;
            if (nb < NP1)
              sVb[(hh * 49 + nb) * 32 + ee] = f2bf(acc[mt][nt][r] + bias[nt]);
          }
      }
    }
  }
  __syncthreads();

  // ---------------- phase 3: attention + gating + em + sampled -----------
  {
    const int wh   = t >> 6;
    const int lane = t & 63;
    const bool act = lane < NP1;
    const int i    = act ? lane : 0;

    float4 q0, q1, q2, q3, q4, q5, q6, q7;
#define LDQ4(Q, E)                                        \
    Q.x = bf2f(sQTb[((wh * 32) + (E) + 0) * 49 + i]);     \
    Q.y = bf2f(sQTb[((wh * 32) + (E) + 1) * 49 + i]);     \
    Q.z = bf2f(sQTb[((wh * 32) + (E) + 2) * 49 + i]);     \
    Q.w = bf2f(sQTb[((wh * 32) + (E) + 3) * 49 + i]);
    LDQ4(q0, 0)  LDQ4(q1, 4)  LDQ4(q2, 8)  LDQ4(q3, 12)
    LDQ4(q4, 16) LDQ4(q5, 20) LDQ4(q6, 24) LDQ4(q7, 28)
#undef LDQ4

    const float mi = act ? sM[i] : 0.f;
    const bool mj = act ? (sM[lane] > 0.f) : false;
    const unsigned long long mbits = __ballot(mj);
    const bool rowok = mi > 0.f;

    float m = -1e30f, l = 0.f;
    float4 a0, a1, a2, a3, a4, a5, a6, a7;
    a0 = a1 = a2 = a3 = a4 = a5 = a6 = a7 = make_float4(0.f, 0.f, 0.f, 0.f);

    for (int j = 0; j < NP1; ++j) {
      const float4* kr = (const float4*)&sKf[(wh * 49 + j) * 32];
      const float4 k0 = kr[0], k1 = kr[1], k2 = kr[2], k3 = kr[3];
      const float4 k4 = kr[4], k5 = kr[5], k6 = kr[6], k7 = kr[7];
      float s = DOT4(q0, k0) + DOT4(q1, k1) + DOT4(q2, k2) + DOT4(q3, k3) +
                DOT4(q4, k4) + DOT4(q5, k5) + DOT4(q6, k6) + DOT4(q7, k7);
      const bool ok = rowok && ((mbits >> j) & 1ull);
      s = ok ? s : -1e9f;
      const float mnew = fmaxf(m, s);
      const float al = expf(m - mnew);
      const float p  = expf(s - mnew);
      m = mnew;
      l = l * al + p;
      const uint4* vr = (const uint4*)&sVb[(wh * 49 + j) * 32];
      const uint4 u0 = vr[0], u1 = vr[1], u2 = vr[2], u3 = vr[3];
      OFMAU(a0, al, p, u0.x, u0.y) OFMAU(a1, al, p, u0.z, u0.w)
      OFMAU(a2, al, p, u1.x, u1.y) OFMAU(a3, al, p, u1.z, u1.w)
      OFMAU(a4, al, p, u2.x, u2.y) OFMAU(a5, al, p, u2.z, u2.w)
      OFMAU(a6, al, p, u3.x, u3.y) OFMAU(a7, al, p, u3.z, u3.w)
    }
    {
      const float linv = 1.0f / l;
      a0.x *= linv; a0.y *= linv; a0.z *= linv; a0.w *= linv;
      a1.x *= linv; a1.y *= linv; a1.z *= linv; a1.w *= linv;
      a2.x *= linv; a2.y *= linv; a2.z *= linv; a2.w *= linv;
      a3.x *= linv; a3.y *= linv; a3.z *= linv; a3.w *= linv;
      a4.x *= linv; a4.y *= linv; a4.z *= linv; a4.w *= linv;
      a5.x *= linv; a5.y *= linv; a5.z *= linv; a5.w *= linv;
      a6.x *= linv; a6.y *= linv; a6.z *= linv; a6.w *= linv;
      a7.x *= linv; a7.y *= linv; a7.z *= linv; a7.w *= linv;
    }

    float s2 = sB2;
    for (int f = 0; f < 32; ++f) {
      const float4* wr = (const float4*)&sW1t[f * 32];
      const float4 w0 = wr[0], w1 = wr[1], w2 = wr[2], w3 = wr[3];
      const float4 w4 = wr[4], w5 = wr[5], w6 = wr[6], w7 = wr[7];
      float g = sB1[f] +
          DOT4(a0, w0) + DOT4(a1, w1) + DOT4(a2, w2) + DOT4(a3, w3) +
          DOT4(a4, w4) + DOT4(a5, w5) + DOT4(a6, w6) + DOT4(a7, w7);
      s2 += fmaxf(g, 0.f) * sW2s[f];
    }

    const float v0s = act ? s2 : -1e30f;
    float mx2 = v0s;
#pragma unroll
    for (int md = 32; md; md >>= 1) mx2 = fmaxf(mx2, __shfl_xor(mx2, md));
    float p = act ? expf(v0s - mx2) : 0.f;
    float ps = p;
#pragma unroll
    for (int md = 32; md; md >>= 1) ps += __shfl_xor(ps, md);
    float em = (p / ps) * mi;
    float es = em;
#pragma unroll
    for (int md = 32; md; md >>= 1) es += __shfl_xor(es, md);
    em = em / (es + 1e-10f);

    const int base = ((bb * 48 + tg) * 4 + wh) * 49;
    if (act) out[base + lane] = em;

    const float lg = logf(em + 1e-10f);
    const float gn = gumbel_noise((unsigned)(base + lane));
    const float z = act ? (lg + gn) : -1e30f;
    float mx3 = z;
#pragma unroll
    for (int md = 32; md; md >>= 1) mx3 = fmaxf(mx3, __shfl_xor(mx3, md));
    float p3 = act ? expf(z - mx3) : 0.f;
    float ps3 = p3;
#pragma unroll
    for (int md = 32; md; md >>= 1) ps3 += __shfl_xor(ps3, md);
    if (act) out[NOUT + base + lane] = p3 / ps3;
  }
}

extern "C" void kernel_launch(void* const* d_in, const int* in_sizes, int n_in,
                              void* d_out, int out_size, void* d_ws, size_t ws_size,
                              hipStream_t stream) {
  (void)in_sizes; (void)n_in; (void)out_size; (void)d_ws; (void)ws_size;
  const float* x    = (const float*)d_in[0];
  const float* A    = (const float*)d_in[1];
  const float* am   = (const float*)d_in[2];
  const float* Wemb = (const float*)d_in[3];
  const float* bemb = (const float*)d_in[4];
  const float* gm   = (const float*)d_in[5];
  const float* bt   = (const float*)d_in[6];
  const float* Wqkv = (const float*)d_in[7];
  const float* bqkv = (const float*)d_in[8];
  const float* W1   = (const float*)d_in[9];
  const float* b1   = (const float*)d_in[10];
  const float* W2   = (const float*)d_in[11];
  const float* b2   = (const float*)d_in[12];
  convert_wqkv_kernel<<<192, 256, 0, stream>>>(Wqkv);
  dim3 grid(T_N, T_B);
  edge_selector_kernel<<<grid, 256, 0, stream>>>(
      x, A, am, Wemb, bemb, gm, bt, Wqkv, bqkv, W1, b1, W2, b2, (float*)d_out);
}

// Round 7
// 785.905 us; speedup vs baseline: 7.7578x; 1.0615x over previous
//
#include <hip/hip_runtime.h>
#include <cstdint>
#include <cstddef>

#define DEVI __device__ __forceinline__

namespace {

constexpr int T_B = 128;
constexpr int T_N = 48;
constexpr int NP1 = 49;          // n+1 (ghost node)
constexpr int NOUT = T_B * T_N * 4 * NP1;   // 1,204,224 per output tensor

using short8 = __attribute__((ext_vector_type(8))) short;   // 8 bf16
using f32x4  = __attribute__((ext_vector_type(4))) float;

DEVI unsigned rotl(unsigned x, int d) { return (x << d) | (x >> (32 - d)); }

// JAX threefry, PARTITIONABLE mode: counter (0, i), output = x0 ^ x1.
DEVI float gumbel_noise(unsigned idx) {
  unsigned x0 = 0u, x1 = idx;
  const unsigned k0 = 0u, k1 = 42u, k2 = 0x1BD11BDAu ^ 0u ^ 42u;
  x0 += k0; x1 += k1;
#define TF_R(rr) { x0 += x1; x1 = rotl(x1, rr); x1 ^= x0; }
  TF_R(13) TF_R(15) TF_R(26) TF_R(6)   x0 += k1; x1 += k2 + 1u;
  TF_R(17) TF_R(29) TF_R(16) TF_R(24)  x0 += k2; x1 += k0 + 2u;
  TF_R(13) TF_R(15) TF_R(26) TF_R(6)   x0 += k0; x1 += k1 + 3u;
  TF_R(17) TF_R(29) TF_R(16) TF_R(24)  x0 += k1; x1 += k2 + 4u;
  TF_R(13) TF_R(15) TF_R(26) TF_R(6)   x0 += k2; x1 += k0 + 5u;
#undef TF_R
  const unsigned bits = x0 ^ x1;
  float u = __uint_as_float((bits >> 9) | 0x3f800000u) - 1.0f;
  u = fmaxf(u, 0.0f);
  const float ex = -log1pf(-u);
  return -logf(ex);
}

// fp32 -> bf16 round-to-nearest-even
DEVI unsigned short f2bf(float f) {
  const unsigned u = __float_as_uint(f);
  return (unsigned short)((u + 0x7fffu + ((u >> 16) & 1u)) >> 16);
}
DEVI float bf2f(unsigned short u) { return __uint_as_float(((unsigned)u) << 16); }

#define DOT4(Aa, Bb) ((Aa).x * (Bb).x + (Aa).y * (Bb).y + (Aa).z * (Bb).z + (Aa).w * (Bb).w)

// acc = acc*al + p*v
#define OFMA4(Aa, AL, P, Vv)                       \
  (Aa).x = (Aa).x * (AL) + (P) * (Vv).x;           \
  (Aa).y = (Aa).y * (AL) + (P) * (Vv).y;           \
  (Aa).z = (Aa).z * (AL) + (P) * (Vv).z;           \
  (Aa).w = (Aa).w * (AL) + (P) * (Vv).w;

// Arena byte offsets
constexpr int FB_H = 0;           // featH ushort[64][104] = 13312 B
constexpr int FB_L = 13312;       // featL ushort[64][104] = 13312 B
constexpr int EH   = 26624;       // E hi ushort, [64 rows][256 B] swizzled
constexpr int EL   = 43008;       // E lo                       (ends 59392)
constexpr int AMO  = 26624;       // sAM float[48][48] (dead before E write)
constexpr int QTO  = 0;           // ph3: QT bf16 [4*32*49]  = 12544 B
constexpr int VVO  = 12544;       // ph3: V  fp32 [4*49*32]  = 25088 B
constexpr int KKO  = 37632;       // ph3: K  fp32 [4*49*32]  = 25088 B
constexpr int WTO  = 62720;       // W1t float[1024] = 4096 B (ends 66816)
constexpr int ARENA_BYTES = 66816;

}  // namespace

// Transposed bf16 hi/lo weights (L2-resident).
// g_Wt: W_qkv^T  [384 n][128 k] hi at 0, lo at +49152 shorts
// g_We: W_embed^T[128 c][ 96 k] hi at 0, lo at +12288 shorts
__device__ __align__(16) unsigned short g_Wt[2 * 384 * 128];
__device__ __align__(16) unsigned short g_We[2 * 128 * 96];

__global__ void convert_weights_kernel(const float* __restrict__ Wqkv,
                                       const float* __restrict__ Wemb) {
  const int tid = blockIdx.x * 256 + threadIdx.x;
  if (tid < 49152) {
    const int n = tid >> 7, k = tid & 127;
    const float w = Wqkv[k * 384 + n];
    const unsigned short hi = f2bf(w);
    g_Wt[n * 128 + k] = hi;
    g_Wt[49152 + n * 128 + k] = f2bf(w - bf2f(hi));
  } else if (tid < 61440) {
    const int t2 = tid - 49152;
    const int c = t2 / 96, k = t2 - c * 96;
    const float w = Wemb[k * 128 + c];
    const unsigned short hi = f2bf(w);
    g_We[c * 96 + k] = hi;
    g_We[12288 + c * 96 + k] = f2bf(w - bf2f(hi));
  }
}

// One block per (batch, target).
//  0: masks; feat -> bf16 hi/lo [64][104] (pad rows zeroed); small weights
//  1: embed GEMM via MFMA split-bf16 (4 waves x 2 N-tiles x 4 M-tiles x 3 K),
//     LN on C-fragments: 16-lane shfl reduce + cross-wave sLN staging,
//     output E bf16 hi/lo [64][128] XOR-swizzled
//  2: qkv = E @ Wqkv via MFMA split-bf16; Q bf16 transposed (over dead feat,
//     pre-barrier), K/V fp32 post-barrier (they overlap E)
//  3: per-head wave, online softmax + PV (named float4 state only — R5
//     lesson: runtime-indexed arrays go to scratch; V fp32 so PV is pure
//     FMA, no bf16 unpack), gating MLP, em softmax, threefry gumbel.
// LDS ~69 KB -> 2 blocks/CU.
__global__ __launch_bounds__(256, 2) void edge_selector_kernel(
    const float* __restrict__ x, const float* __restrict__ A,
    const float* __restrict__ amask, const float* __restrict__ Wemb,
    const float* __restrict__ bemb, const float* __restrict__ gamma_,
    const float* __restrict__ beta_, const float* __restrict__ Wqkv,
    const float* __restrict__ bqkv, const float* __restrict__ W1g,
    const float* __restrict__ b1g, const float* __restrict__ W2g,
    const float* __restrict__ b2g, float* __restrict__ out) {
  __shared__ __align__(16) unsigned char ARENA[ARENA_BYTES];
  __shared__ float sLN[4][64][2];   // per-wave row partials (sum, sumsq)
  __shared__ float sM[NP1];
  __shared__ float sMp[48];
  __shared__ float sB1[32];
  __shared__ float sW2s[32];
  __shared__ float sB2;

  unsigned short* const featH = (unsigned short*)(ARENA + FB_H);
  unsigned short* const featL = (unsigned short*)(ARENA + FB_L);
  float* const sAM  = (float*)(ARENA + AMO);
  unsigned short* const sQTb = (unsigned short*)(ARENA + QTO);
  float* const sVf  = (float*)(ARENA + VVO);
  float* const sKf  = (float*)(ARENA + KKO);
  float* const sW1t = (float*)(ARENA + WTO);

  const int t  = threadIdx.x;
  const int tg = blockIdx.x;
  const int bb = blockIdx.y;

  // ---------------- phase 0a: masks + small weights + feat pad zero ------
  for (int idx = t; idx < 48 * 48; idx += 256) sAM[idx] = amask[bb * 2304 + idx];
  for (int idx = t; idx < 1024; idx += 256) {
    const int e = idx >> 5, f = idx & 31;
    sW1t[f * 32 + e] = W1g[idx];
  }
  {
    // zero feat pad rows 49..63 (15 rows x 104 shorts = 780 dwords per buf)
    unsigned* zh = (unsigned*)(ARENA + FB_H + 49 * 208);
    unsigned* zl = (unsigned*)(ARENA + FB_L + 49 * 208);
    for (int idx = t; idx < 780; idx += 256) { zh[idx] = 0u; zl[idx] = 0u; }
  }
  if (t < 32) { sB1[t] = b1g[t]; sW2s[t] = W2g[t]; }
  if (t == 0) sB2 = b2g[0];
  __syncthreads();
  if (t < 48) {
    float s = 0.f;
    for (int j = 0; j < 48; ++j) s += sAM[t * 48 + j];
    sMp[t] = (s > 0.f) ? 1.f : 0.f;
    sM[t] = sAM[tg * 48 + t];
  }
  if (t == 0) sM[48] = 1.f;
  __syncthreads();

  // ---------------- phase 0b: feat -> bf16 hi/lo -------------------------
  {
    const float mt_ = sMp[tg];
#define WFB(col, val) { const unsigned short hh_ = f2bf(val);            \
    featH[nb * 104 + (col)] = hh_;                                       \
    featL[nb * 104 + (col)] = f2bf((val) - bf2f(hh_)); }
    for (int idx = t; idx < NP1 * 32; idx += 256) {
      const int nb = idx >> 5, e = idx & 31;
      const float xt = x[(bb * 48 + tg) * 32 + e] * mt_;
      float xv = 0.f, av = 0.f;
      if (nb < 48) {
        xv = x[(bb * 48 + nb) * 32 + e] * sMp[nb];
        av = A[(((bb * 48 + nb) * 48) + tg) * 32 + e] * sM[nb];
      }
      WFB(e, xv) WFB(32 + e, xt) WFB(64 + e, av)
    }
#undef WFB
  }
  __syncthreads();

  const int w  = t >> 6;
  const int l  = t & 63;
  const int lm = l & 15, lg = l >> 4;

  // ---------------- phase 1: E = LN(feat @ Wemb + b) via MFMA ------------
  {
    f32x4 eacc[4][2];
#pragma unroll
    for (int mt = 0; mt < 4; ++mt)
#pragma unroll
      for (int nt = 0; nt < 2; ++nt) eacc[mt][nt] = (f32x4){0.f, 0.f, 0.f, 0.f};

#pragma unroll
    for (int ks = 0; ks < 3; ++ks) {
      short8 fh[4], fl[4];
#pragma unroll
      for (int mt = 0; mt < 4; ++mt) {
        const int so = (mt * 16 + lm) * 104 + ks * 32 + lg * 8;
        fh[mt] = *(const short8*)&featH[so];
        fl[mt] = *(const short8*)&featL[so];
      }
#pragma unroll
      for (int nt = 0; nt < 2; ++nt) {
        const int kid = ((w * 2 + nt) * 16 + lm) * 96 + ks * 32 + lg * 8;
        const short8 bh = *(const short8*)&g_We[kid];
        const short8 bl = *(const short8*)&g_We[12288 + kid];
#pragma unroll
        for (int mt = 0; mt < 4; ++mt) {
          eacc[mt][nt] = __builtin_amdgcn_mfma_f32_16x16x32_bf16(fh[mt], bh, eacc[mt][nt], 0, 0, 0);
          eacc[mt][nt] = __builtin_amdgcn_mfma_f32_16x16x32_bf16(fl[mt], bh, eacc[mt][nt], 0, 0, 0);
          eacc[mt][nt] = __builtin_amdgcn_mfma_f32_16x16x32_bf16(fh[mt], bl, eacc[mt][nt], 0, 0, 0);
        }
      }
    }

    const float b0 = bemb[(w * 2 + 0) * 16 + lm];
    const float b1 = bemb[(w * 2 + 1) * 16 + lm];
    // per-row partial stats over this wave's 32 cols, reduced across the
    // 16 lanes (lm) that share (lg): shfl_xor masks 1,2,4,8 stay in-group.
#pragma unroll
    for (int mt = 0; mt < 4; ++mt)
#pragma unroll
      for (int r = 0; r < 4; ++r) {
        const float v0 = eacc[mt][0][r] + b0;
        const float v1 = eacc[mt][1][r] + b1;
        float s  = v0 + v1;
        float qs = v0 * v0 + v1 * v1;
#pragma unroll
        for (int md = 8; md; md >>= 1) {
          s  += __shfl_xor(s, md);
          qs += __shfl_xor(qs, md);
        }
        if (lm == 0) {
          const int row = mt * 16 + lg * 4 + r;
          sLN[w][row][0] = s;
          sLN[w][row][1] = qs;
        }
      }
    __syncthreads();

    const int c0 = (w * 2) * 16 + lm, c1 = c0 + 16;
    const float g0 = gamma_[c0], g1 = gamma_[c1];
    const float be0 = beta_[c0], be1 = beta_[c1];
#pragma unroll
    for (int mt = 0; mt < 4; ++mt)
#pragma unroll
      for (int r = 0; r < 4; ++r) {
        const int row = mt * 16 + lg * 4 + r;
        const float s  = sLN[0][row][0] + sLN[1][row][0] + sLN[2][row][0] + sLN[3][row][0];
        const float qs = sLN[0][row][1] + sLN[1][row][1] + sLN[2][row][1] + sLN[3][row][1];
        const float mu  = s * (1.0f / 128.0f);
        const float var = qs * (1.0f / 128.0f) - mu * mu;
        const float rs  = 1.0f / sqrtf(var + 1e-5f);
        const float o0 = (eacc[mt][0][r] + b0 - mu) * rs * g0 + be0;
        const float o1 = (eacc[mt][1][r] + b1 - mu) * rs * g1 + be1;
        const int sw = (row & 3) << 4;
        const unsigned short h0 = f2bf(o0);
        const unsigned short h1 = f2bf(o1);
        *(unsigned short*)(ARENA + EH + row * 256 + ((c0 * 2) ^ sw)) = h0;
        *(unsigned short*)(ARENA + EL + row * 256 + ((c0 * 2) ^ sw)) = f2bf(o0 - bf2f(h0));
        *(unsigned short*)(ARENA + EH + row * 256 + ((c1 * 2) ^ sw)) = h1;
        *(unsigned short*)(ARENA + EL + row * 256 + ((c1 * 2) ^ sw)) = f2bf(o1 - bf2f(h1));
      }
  }
  __syncthreads();

  // ---------------- phase 2: qkv = E @ Wqkv via MFMA (split bf16) --------
  {
    const float SC = 0.17677669529663687f;  // 1/sqrt(32)

    f32x4 acc[4][6];
#pragma unroll
    for (int mt = 0; mt < 4; ++mt)
#pragma unroll
      for (int nt = 0; nt < 6; ++nt) acc[mt][nt] = (f32x4){0.f, 0.f, 0.f, 0.f};

#pragma unroll
    for (int ks = 0; ks < 4; ++ks) {
      short8 ah[4], alo[4];
#pragma unroll
      for (int mt = 0; mt < 4; ++mt) {
        const int row = mt * 16 + lm;
        const int off = (ks * 64 + lg * 16) ^ ((row & 3) << 4);
        ah[mt]  = *(const short8*)(ARENA + EH + row * 256 + off);
        alo[mt] = *(const short8*)(ARENA + EL + row * 256 + off);
      }
#pragma unroll
      for (int nt = 0; nt < 6; ++nt) {
        const int kid = ((w * 6 + nt) * 16 + lm) * 128 + ks * 32 + lg * 8;
        const short8 bh = *(const short8*)&g_Wt[kid];
        const short8 bl = *(const short8*)&g_Wt[49152 + kid];
#pragma unroll
        for (int mt = 0; mt < 4; ++mt) {
          acc[mt][nt] = __builtin_amdgcn_mfma_f32_16x16x32_bf16(ah[mt],  bh, acc[mt][nt], 0, 0, 0);
          acc[mt][nt] = __builtin_amdgcn_mfma_f32_16x16x32_bf16(alo[mt], bh, acc[mt][nt], 0, 0, 0);
          acc[mt][nt] = __builtin_amdgcn_mfma_f32_16x16x32_bf16(ah[mt],  bl, acc[mt][nt], 0, 0, 0);
        }
      }
    }

    float bias[6];
#pragma unroll
    for (int nt = 0; nt < 6; ++nt) bias[nt] = bqkv[(w * 6 + nt) * 16 + lm];

    const int rb = lg * 4;
    // Q (tiles 0-7): over dead feat region -> safe pre-barrier
#pragma unroll
    for (int nt = 0; nt < 6; ++nt) {
      const int ntg = w * 6 + nt;
      if (ntg < 8) {
        const int c = ntg * 16 + lm;
        const int hh = c >> 5, ee = c & 31;
#pragma unroll
        for (int mt = 0; mt < 4; ++mt)
#pragma unroll
          for (int r = 0; r < 4; ++r) {
            const int nb = mt * 16 + rb + r;
            if (nb < NP1)
              sQTb[(hh * 32 + ee) * 49 + nb] = f2bf((acc[mt][nt][r] + bias[nt]) * SC);
          }
      }
    }
    __syncthreads();   // all E reads done -> K/V may overwrite E region
#pragma unroll
    for (int nt = 0; nt < 6; ++nt) {
      const int ntg = w * 6 + nt;
      const int c = ntg * 16 + lm;
      if (ntg >= 8 && ntg < 16) {
        const int cc = c - 128;
        const int hh = cc >> 5, ee = cc & 31;
#pragma unroll
        for (int mt = 0; mt < 4; ++mt)
#pragma unroll
          for (int r = 0; r < 4; ++r) {
            const int nb = mt * 16 + rb + r;
            if (nb < NP1) sKf[(hh * 49 + nb) * 32 + ee] = acc[mt][nt][r] + bias[nt];
          }
      } else if (ntg >= 16) {
        const int cc = c - 256;
        const int hh = cc >> 5, ee = cc & 31;
#pragma unroll
        for (int mt = 0; mt < 4; ++mt)
#pragma unroll
          for (int r = 0; r < 4; ++r) {
            const int nb = mt * 16 + rb + r;
            if (nb < NP1) sVf[(hh * 49 + nb) * 32 + ee] = acc[mt][nt][r] + bias[nt];
          }
      }
    }
  }
  __syncthreads();

  // ---------------- phase 3: attention + gating + em + sampled -----------
  {
    const int wh   = t >> 6;
    const int lane = t & 63;
    const bool act = lane < NP1;
    const int i    = act ? lane : 0;

    float4 q0, q1, q2, q3, q4, q5, q6, q7;
#define LDQ4(Q, E)                                        \
    Q.x = bf2f(sQTb[((wh * 32) + (E) + 0) * 49 + i]);     \
    Q.y = bf2f(sQTb[((wh * 32) + (E) + 1) * 49 + i]);     \
    Q.z = bf2f(sQTb[((wh * 32) + (E) + 2) * 49 + i]);     \
    Q.w = bf2f(sQTb[((wh * 32) + (E) + 3) * 49 + i]);
    LDQ4(q0, 0)  LDQ4(q1, 4)  LDQ4(q2, 8)  LDQ4(q3, 12)
    LDQ4(q4, 16) LDQ4(q5, 20) LDQ4(q6, 24) LDQ4(q7, 28)
#undef LDQ4

    const float mi = act ? sM[i] : 0.f;
    const bool mj = act ? (sM[lane] > 0.f) : false;
    const unsigned long long mbits = __ballot(mj);
    const bool rowok = mi > 0.f;

    float m = -1e30f, lsum = 0.f;
    float4 a0, a1, a2, a3, a4, a5, a6, a7;
    a0 = a1 = a2 = a3 = a4 = a5 = a6 = a7 = make_float4(0.f, 0.f, 0.f, 0.f);

    for (int j = 0; j < NP1; ++j) {
      const float4* kr = (const float4*)&sKf[(wh * 49 + j) * 32];
      const float4 k0 = kr[0], k1 = kr[1], k2 = kr[2], k3 = kr[3];
      const float4 k4 = kr[4], k5 = kr[5], k6 = kr[6], k7 = kr[7];
      float s = DOT4(q0, k0) + DOT4(q1, k1) + DOT4(q2, k2) + DOT4(q3, k3) +
                DOT4(q4, k4) + DOT4(q5, k5) + DOT4(q6, k6) + DOT4(q7, k7);
      const bool ok = rowok && ((mbits >> j) & 1ull);
      s = ok ? s : -1e9f;
      const float mnew = fmaxf(m, s);
      const float al = expf(m - mnew);
      const float p  = expf(s - mnew);
      m = mnew;
      lsum = lsum * al + p;
      const float4* vr = (const float4*)&sVf[(wh * 49 + j) * 32];
      const float4 v0 = vr[0], v1 = vr[1], v2 = vr[2], v3 = vr[3];
      const float4 v4 = vr[4], v5 = vr[5], v6 = vr[6], v7 = vr[7];
      OFMA4(a0, al, p, v0) OFMA4(a1, al, p, v1)
      OFMA4(a2, al, p, v2) OFMA4(a3, al, p, v3)
      OFMA4(a4, al, p, v4) OFMA4(a5, al, p, v5)
      OFMA4(a6, al, p, v6) OFMA4(a7, al, p, v7)
    }
    {
      const float linv = 1.0f / lsum;
      a0.x *= linv; a0.y *= linv; a0.z *= linv; a0.w *= linv;
      a1.x *= linv; a1.y *= linv; a1.z *= linv; a1.w *= linv;
      a2.x *= linv; a2.y *= linv; a2.z *= linv; a2.w *= linv;
      a3.x *= linv; a3.y *= linv; a3.z *= linv; a3.w *= linv;
      a4.x *= linv; a4.y *= linv; a4.z *= linv; a4.w *= linv;
      a5.x *= linv; a5.y *= linv; a5.z *= linv; a5.w *= linv;
      a6.x *= linv; a6.y *= linv; a6.z *= linv; a6.w *= linv;
      a7.x *= linv; a7.y *= linv; a7.z *= linv; a7.w *= linv;
    }

    float s2 = sB2;
    for (int f = 0; f < 32; ++f) {
      const float4* wr = (const float4*)&sW1t[f * 32];
      const float4 w0 = wr[0], w1 = wr[1], w2 = wr[2], w3 = wr[3];
      const float4 w4 = wr[4], w5 = wr[5], w6 = wr[6], w7 = wr[7];
      float g = sB1[f] +
          DOT4(a0, w0) + DOT4(a1, w1) + DOT4(a2, w2) + DOT4(a3, w3) +
          DOT4(a4, w4) + DOT4(a5, w5) + DOT4(a6, w6) + DOT4(a7, w7);
      s2 += fmaxf(g, 0.f) * sW2s[f];
    }

    const float v0s = act ? s2 : -1e30f;
    float mx2 = v0s;
#pragma unroll
    for (int md = 32; md; md >>= 1) mx2 = fmaxf(mx2, __shfl_xor(mx2, md));
    float p = act ? expf(v0s - mx2) : 0.f;
    float ps = p;
#pragma unroll
    for (int md = 32; md; md >>= 1) ps += __shfl_xor(ps, md);
    float em = (p / ps) * mi;
    float es = em;
#pragma unroll
    for (int md = 32; md; md >>= 1) es += __shfl_xor(es, md);
    em = em / (es + 1e-10f);

    const int base = ((bb * 48 + tg) * 4 + wh) * 49;
    if (act) out[base + lane] = em;

    const float lg2 = logf(em + 1e-10f);
    const float gn = gumbel_noise((unsigned)(base + lane));
    const float z = act ? (lg2 + gn) : -1e30f;
    float mx3 = z;
#pragma unroll
    for (int md = 32; md; md >>= 1) mx3 = fmaxf(mx3, __shfl_xor(mx3, md));
    float p3 = act ? expf(z - mx3) : 0.f;
    float ps3 = p3;
#pragma unroll
    for (int md = 32; md; md >>= 1) ps3 += __shfl_xor(ps3, md);
    if (act) out[NOUT + base + lane] = p3 / ps3;
  }
}

extern "C" void kernel_launch(void* const* d_in, const int* in_sizes, int n_in,
                              void* d_out, int out_size, void* d_ws, size_t ws_size,
                              hipStream_t stream) {
  (void)in_sizes; (void)n_in; (void)out_size; (void)d_ws; (void)ws_size;
  const float* x    = (const float*)d_in[0];
  const float* A    = (const float*)d_in[1];
  const float* am   = (const float*)d_in[2];
  const float* Wemb = (const float*)d_in[3];
  const float* bemb = (const float*)d_in[4];
  const float* gm   = (const float*)d_in[5];
  const float* bt   = (const float*)d_in[6];
  const float* Wqkv = (const float*)d_in[7];
  const float* bqkv = (const float*)d_in[8];
  const float* W1   = (const float*)d_in[9];
  const float* b1   = (const float*)d_in[10];
  const float* W2   = (const float*)d_in[11];
  const float* b2   = (const float*)d_in[12];
  convert_weights_kernel<<<240, 256, 0, stream>>>(Wqkv, Wemb);
  dim3 grid(T_N, T_B);
  edge_selector_kernel<<<grid, 256, 0, stream>>>(
      x, A, am, Wemb, bemb, gm, bt, Wqkv, bqkv, W1, b1, W2, b2, (float*)d_out);
}

// Round 8
// 602.124 us; speedup vs baseline: 10.1257x; 1.3052x over previous
//
#include <hip/hip_runtime.h>
#include <cstdint>
#include <cstddef>

#define DEVI __device__ __forceinline__

namespace {

constexpr int T_B = 128;
constexpr int T_N = 48;
constexpr int NP1 = 49;          // n+1 (ghost node)
constexpr int NOUT = T_B * T_N * 4 * NP1;   // 1,204,224 per output tensor

using short8 = __attribute__((ext_vector_type(8))) short;   // 8 bf16
using f32x4  = __attribute__((ext_vector_type(4))) float;

DEVI unsigned rotl(unsigned x, int d) { return (x << d) | (x >> (32 - d)); }

// JAX threefry, PARTITIONABLE mode: counter (0, i), output = x0 ^ x1.
DEVI float gumbel_noise(unsigned idx) {
  unsigned x0 = 0u, x1 = idx;
  const unsigned k0 = 0u, k1 = 42u, k2 = 0x1BD11BDAu ^ 0u ^ 42u;
  x0 += k0; x1 += k1;
#define TF_R(rr) { x0 += x1; x1 = rotl(x1, rr); x1 ^= x0; }
  TF_R(13) TF_R(15) TF_R(26) TF_R(6)   x0 += k1; x1 += k2 + 1u;
  TF_R(17) TF_R(29) TF_R(16) TF_R(24)  x0 += k2; x1 += k0 + 2u;
  TF_R(13) TF_R(15) TF_R(26) TF_R(6)   x0 += k0; x1 += k1 + 3u;
  TF_R(17) TF_R(29) TF_R(16) TF_R(24)  x0 += k1; x1 += k2 + 4u;
  TF_R(13) TF_R(15) TF_R(26) TF_R(6)   x0 += k2; x1 += k0 + 5u;
#undef TF_R
  const unsigned bits = x0 ^ x1;
  float u = __uint_as_float((bits >> 9) | 0x3f800000u) - 1.0f;
  u = fmaxf(u, 0.0f);
  const float ex = -log1pf(-u);
  return -logf(ex);
}

// fp32 -> bf16 round-to-nearest-even
DEVI unsigned short f2bf(float f) {
  const unsigned u = __float_as_uint(f);
  return (unsigned short)((u + 0x7fffu + ((u >> 16) & 1u)) >> 16);
}
DEVI float bf2f(unsigned short u) { return __uint_as_float(((unsigned)u) << 16); }

#define DOT4(Aa, Bb) ((Aa).x * (Bb).x + (Aa).y * (Bb).y + (Aa).z * (Bb).z + (Aa).w * (Bb).w)

// Arena byte offsets (single overlaid arena; liveness commented per phase)
constexpr int FH  = 0;       // feat hi ushort[64][104] = 13312   (ph0-1)
constexpr int FL  = 13312;   // feat lo                  (end 26624)
constexpr int EHO = 0;       // E hi [64 rows][256 B] swizzled    (ph1-2, over feat)
constexpr int ELO = 16384;   // E lo                     (end 32768)
constexpr int AMO = 32768;   // sAM f32[48][48] = 9216            (ph0 only)
constexpr int SLN = 32768;   // sLN f32[4][64][2] = 2048          (ph1, over sAM)
constexpr int QBO = 0;       // Qb bf16 [4][64][32] = 16384       (ph2-3a, over E hi)
constexpr int KBO = 16384;   // Kb bf16 [4][64][32] = 16384       (ph2-3a, over E lo)
constexpr int VTO = 32768;   // VT bf16 [4][32][64] = 16384       (ph2-3b, over sAM) end 49152
constexpr int PBO = 0;       // P  bf16 [4][64][64] = 32768       (ph3a-b, over Qb+Kb)
constexpr int A2O = 0;       // A2 f32  [4][64][34] = 34816       (ph3b-c, over P/VT0)
constexpr int W1O = 34816;   // W1t f32 [32][32] = 4096           (ph3c, over dead VT)
constexpr int ARENA_BYTES = 49152;

}  // namespace

// Transposed bf16 hi/lo weights (L2-resident).
__device__ __align__(16) unsigned short g_Wt[2 * 384 * 128];
__device__ __align__(16) unsigned short g_We[2 * 128 * 96];

__global__ void convert_weights_kernel(const float* __restrict__ Wqkv,
                                       const float* __restrict__ Wemb) {
  const int tid = blockIdx.x * 256 + threadIdx.x;
  if (tid < 49152) {
    const int n = tid >> 7, k = tid & 127;
    const float w = Wqkv[k * 384 + n];
    const unsigned short hi = f2bf(w);
    g_Wt[n * 128 + k] = hi;
    g_Wt[49152 + n * 128 + k] = f2bf(w - bf2f(hi));
  } else if (tid < 61440) {
    const int t2 = tid - 49152;
    const int c = t2 / 96, k = t2 - c * 96;
    const float w = Wemb[k * 128 + c];
    const unsigned short hi = f2bf(w);
    g_We[c * 96 + k] = hi;
    g_We[12288 + c * 96 + k] = f2bf(w - bf2f(hi));
  }
}

// One block per (batch, target). All big math on MFMA; LDS arena 48 KB
// overlaid -> ~49.9 KB total -> 3 blocks/CU (launch_bounds(256,3)).
//  0: masks; feat bf16 hi/lo; pads zeroed
//  1: E = LN(feat @ Wemb) MFMA split-bf16; E overwrites feat post-barrier
//  2: qkv MFMA split-bf16 -> Qb/Kb bf16 (swizzled k), VT bf16 (swizzled j,
//     fully pre-zeroed: pad j cols MUST be 0 as MFMA B-operand)
//  3a: S = Q·K^T via MFMA (16/wave, wave=head); masked softmax on C-frags
//      (-1e9 for masked j<49, -inf for pad j -> exact uniform fallback);
//      P bf16 -> LDS (swizzled); linv kept in regs (lane-matched C layouts)
//  3b: A2 = P·V via MFMA (16/wave); scale by linv; A2 fp32 -> LDS [.][34]
//  3c: per-lane gating MLP + em softmax + threefry gumbel (proven R5 code)
__global__ __launch_bounds__(256, 3) void edge_selector_kernel(
    const float* __restrict__ x, const float* __restrict__ A,
    const float* __restrict__ amask, const float* __restrict__ Wemb,
    const float* __restrict__ bemb, const float* __restrict__ gamma_,
    const float* __restrict__ beta_, const float* __restrict__ Wqkv,
    const float* __restrict__ bqkv, const float* __restrict__ W1g,
    const float* __restrict__ b1g, const float* __restrict__ W2g,
    const float* __restrict__ b2g, float* __restrict__ out) {
  __shared__ __align__(16) unsigned char ARENA[ARENA_BYTES];
  __shared__ float sM[64];     // mask row of tg, ghost=1, pads 49-63 = 0
  __shared__ float sMp[48];
  __shared__ float sB1[32];
  __shared__ float sW2s[32];
  __shared__ float sB2;

  unsigned short* const featH = (unsigned short*)(ARENA + FH);
  unsigned short* const featL = (unsigned short*)(ARENA + FL);
  float* const sAM  = (float*)(ARENA + AMO);
  float* const sLNa = (float*)(ARENA + SLN);

  const int t  = threadIdx.x;
  const int tg = blockIdx.x;
  const int bb = blockIdx.y;

  // ---------------- phase 0a: masks + small weights + pad zero -----------
  for (int idx = t; idx < 48 * 48; idx += 256) sAM[idx] = amask[bb * 2304 + idx];
  {
    unsigned* zh = (unsigned*)(ARENA + FH + 49 * 208);
    unsigned* zl = (unsigned*)(ARENA + FL + 49 * 208);
    for (int idx = t; idx < 780; idx += 256) { zh[idx] = 0u; zl[idx] = 0u; }
  }
  if (t >= 49 && t < 64) sM[t] = 0.f;   // pads
  if (t < 32) { sB1[t] = b1g[t]; sW2s[t] = W2g[t]; }
  if (t == 0) sB2 = b2g[0];
  __syncthreads();
  if (t < 48) {
    float s = 0.f;
    for (int j = 0; j < 48; ++j) s += sAM[t * 48 + j];
    sMp[t] = (s > 0.f) ? 1.f : 0.f;
    sM[t] = sAM[tg * 48 + t];
  }
  if (t == 48) sM[48] = 1.f;   // ghost always attendable
  __syncthreads();

  // ---------------- phase 0b: feat -> bf16 hi/lo -------------------------
  {
    const float mt_ = sMp[tg];
#define WFB(col, val) { const unsigned short hh_ = f2bf(val);            \
    featH[nb * 104 + (col)] = hh_;                                       \
    featL[nb * 104 + (col)] = f2bf((val) - bf2f(hh_)); }
    for (int idx = t; idx < NP1 * 32; idx += 256) {
      const int nb = idx >> 5, e = idx & 31;
      const float xt = x[(bb * 48 + tg) * 32 + e] * mt_;
      float xv = 0.f, av = 0.f;
      if (nb < 48) {
        xv = x[(bb * 48 + nb) * 32 + e] * sMp[nb];
        av = A[(((bb * 48 + nb) * 48) + tg) * 32 + e] * sM[nb];
      }
      WFB(e, xv) WFB(32 + e, xt) WFB(64 + e, av)
    }
#undef WFB
  }
  __syncthreads();

  const int w  = t >> 6;
  const int l  = t & 63;
  const int lm = l & 15, lg = l >> 4;

  // ---------------- phase 1: E = LN(feat @ Wemb + b) via MFMA ------------
  {
    f32x4 eacc[4][2];
#pragma unroll
    for (int mt = 0; mt < 4; ++mt)
#pragma unroll
      for (int nt = 0; nt < 2; ++nt) eacc[mt][nt] = (f32x4){0.f, 0.f, 0.f, 0.f};

#pragma unroll
    for (int ks = 0; ks < 3; ++ks) {
      short8 fh[4], fl[4];
#pragma unroll
      for (int mt = 0; mt < 4; ++mt) {
        const int so = (mt * 16 + lm) * 104 + ks * 32 + lg * 8;
        fh[mt] = *(const short8*)&featH[so];
        fl[mt] = *(const short8*)&featL[so];
      }
#pragma unroll
      for (int nt = 0; nt < 2; ++nt) {
        const int kid = ((w * 2 + nt) * 16 + lm) * 96 + ks * 32 + lg * 8;
        const short8 bh = *(const short8*)&g_We[kid];
        const short8 bl = *(const short8*)&g_We[12288 + kid];
#pragma unroll
        for (int mt = 0; mt < 4; ++mt) {
          eacc[mt][nt] = __builtin_amdgcn_mfma_f32_16x16x32_bf16(fh[mt], bh, eacc[mt][nt], 0, 0, 0);
          eacc[mt][nt] = __builtin_amdgcn_mfma_f32_16x16x32_bf16(fl[mt], bh, eacc[mt][nt], 0, 0, 0);
          eacc[mt][nt] = __builtin_amdgcn_mfma_f32_16x16x32_bf16(fh[mt], bl, eacc[mt][nt], 0, 0, 0);
        }
      }
    }

    const float b0 = bemb[(w * 2 + 0) * 16 + lm];
    const float b1 = bemb[(w * 2 + 1) * 16 + lm];
#pragma unroll
    for (int mt = 0; mt < 4; ++mt)
#pragma unroll
      for (int r = 0; r < 4; ++r) {
        const float v0 = eacc[mt][0][r] + b0;
        const float v1 = eacc[mt][1][r] + b1;
        float s  = v0 + v1;
        float qs = v0 * v0 + v1 * v1;
#pragma unroll
        for (int md = 8; md; md >>= 1) {
          s  += __shfl_xor(s, md);
          qs += __shfl_xor(qs, md);
        }
        if (lm == 0) {
          const int row = mt * 16 + lg * 4 + r;
          sLNa[(w * 64 + row) * 2 + 0] = s;
          sLNa[(w * 64 + row) * 2 + 1] = qs;
        }
      }
    __syncthreads();   // feat reads done everywhere; sLN visible

    const int c0 = (w * 2) * 16 + lm, c1 = c0 + 16;
    const float g0 = gamma_[c0], g1 = gamma_[c1];
    const float be0 = beta_[c0], be1 = beta_[c1];
#pragma unroll
    for (int mt = 0; mt < 4; ++mt)
#pragma unroll
      for (int r = 0; r < 4; ++r) {
        const int row = mt * 16 + lg * 4 + r;
        const float s  = sLNa[row * 2 + 0] + sLNa[(64 + row) * 2 + 0] +
                         sLNa[(128 + row) * 2 + 0] + sLNa[(192 + row) * 2 + 0];
        const float qs = sLNa[row * 2 + 1] + sLNa[(64 + row) * 2 + 1] +
                         sLNa[(128 + row) * 2 + 1] + sLNa[(192 + row) * 2 + 1];
        const float mu  = s * (1.0f / 128.0f);
        const float var = qs * (1.0f / 128.0f) - mu * mu;
        const float rs  = 1.0f / sqrtf(var + 1e-5f);
        const float o0 = (eacc[mt][0][r] + b0 - mu) * rs * g0 + be0;
        const float o1 = (eacc[mt][1][r] + b1 - mu) * rs * g1 + be1;
        const int sw = (row & 3) << 4;
        const unsigned short h0 = f2bf(o0);
        const unsigned short h1 = f2bf(o1);
        *(unsigned short*)(ARENA + EHO + row * 256 + ((c0 * 2) ^ sw)) = h0;
        *(unsigned short*)(ARENA + ELO + row * 256 + ((c0 * 2) ^ sw)) = f2bf(o0 - bf2f(h0));
        *(unsigned short*)(ARENA + EHO + row * 256 + ((c1 * 2) ^ sw)) = h1;
        *(unsigned short*)(ARENA + ELO + row * 256 + ((c1 * 2) ^ sw)) = f2bf(o1 - bf2f(h1));
      }
    // zero E pad rows 49-63 (hi + lo): 960 dwords each
    for (int idx = t; idx < 1920; idx += 256) {
      const int buf = (idx >= 960) ? ELO : EHO;
      const int k2 = (idx >= 960) ? idx - 960 : idx;
      *(unsigned*)(ARENA + buf + (49 + (k2 >> 6)) * 256 + (k2 & 63) * 4) = 0u;
    }
  }
  __syncthreads();

  // ---------------- phase 2: qkv = E @ Wqkv via MFMA (split bf16) --------
  {
    const float SC = 0.17677669529663687f;  // 1/sqrt(32)

    f32x4 acc[4][6];
#pragma unroll
    for (int mt = 0; mt < 4; ++mt)
#pragma unroll
      for (int nt = 0; nt < 6; ++nt) acc[mt][nt] = (f32x4){0.f, 0.f, 0.f, 0.f};

#pragma unroll
    for (int ks = 0; ks < 4; ++ks) {
      short8 ah[4], alo[4];
#pragma unroll
      for (int mt = 0; mt < 4; ++mt) {
        const int row = mt * 16 + lm;
        const int off = (ks * 64 + lg * 16) ^ ((row & 3) << 4);
        ah[mt]  = *(const short8*)(ARENA + EHO + row * 256 + off);
        alo[mt] = *(const short8*)(ARENA + ELO + row * 256 + off);
      }
#pragma unroll
      for (int nt = 0; nt < 6; ++nt) {
        const int kid = ((w * 6 + nt) * 16 + lm) * 128 + ks * 32 + lg * 8;
        const short8 bh = *(const short8*)&g_Wt[kid];
        const short8 bl = *(const short8*)&g_Wt[49152 + kid];
#pragma unroll
        for (int mt = 0; mt < 4; ++mt) {
          acc[mt][nt] = __builtin_amdgcn_mfma_f32_16x16x32_bf16(ah[mt],  bh, acc[mt][nt], 0, 0, 0);
          acc[mt][nt] = __builtin_amdgcn_mfma_f32_16x16x32_bf16(alo[mt], bh, acc[mt][nt], 0, 0, 0);
          acc[mt][nt] = __builtin_amdgcn_mfma_f32_16x16x32_bf16(ah[mt],  bl, acc[mt][nt], 0, 0, 0);
        }
      }
    }

    // pre-zero VT (over dead sAM/sLN; NOT over E) before the barrier
    { unsigned* vz = (unsigned*)(ARENA + VTO);
      for (int idx = t; idx < 4096; idx += 256) vz[idx] = 0u; }
    __syncthreads();   // all E reads done; VT zero visible

    float bias[6];
#pragma unroll
    for (int nt = 0; nt < 6; ++nt) bias[nt] = bqkv[(w * 6 + nt) * 16 + lm];

#pragma unroll
    for (int nt = 0; nt < 6; ++nt) {
      const int ntg = w * 6 + nt;
      const int c = ntg * 16 + lm;
#pragma unroll
      for (int mt = 0; mt < 4; ++mt)
#pragma unroll
        for (int r = 0; r < 4; ++r) {
          const int nb = mt * 16 + lg * 4 + r;
          if (nb < NP1) {
            const float v = acc[mt][nt][r] + bias[nt];
            if (ntg < 8) {            // Q: scaled bf16, k-swizzled
              const int h = c >> 5, k = c & 31;
              *(unsigned short*)(ARENA + QBO +
                ((h * 64 + nb) * 32 + (k ^ ((nb & 3) << 3))) * 2) = f2bf(v * SC);
            } else if (ntg < 16) {    // K: bf16, k-swizzled
              const int cc = c - 128, h = cc >> 5, k = cc & 31;
              *(unsigned short*)(ARENA + KBO +
                ((h * 64 + nb) * 32 + (k ^ ((nb & 3) << 3))) * 2) = f2bf(v);
            } else {                  // V^T: bf16, j-swizzled
              const int cc = c - 256, h = cc >> 5, e = cc & 31;
              *(unsigned short*)(ARENA + VTO +
                ((h * 32 + e) * 64 + (nb ^ ((e & 7) << 3))) * 2) = f2bf(v);
            }
          }
        }
    }
  }
  __syncthreads();

  // ---------------- phase 3a: S = Q·K^T (MFMA) + softmax -> P ------------
  const int wh = w;   // wave = head
  f32x4 linv[4];
  {
    f32x4 sacc[4][4];
#pragma unroll
    for (int mt = 0; mt < 4; ++mt)
#pragma unroll
      for (int nt = 0; nt < 4; ++nt) sacc[mt][nt] = (f32x4){0.f, 0.f, 0.f, 0.f};

    const int koff = ((lg * 8) ^ ((lm & 3) << 3)) * 2;
    short8 qa[4];
#pragma unroll
    for (int mt = 0; mt < 4; ++mt)
      qa[mt] = *(const short8*)(ARENA + QBO + wh * 4096 + (mt * 16 + lm) * 64 + koff);
#pragma unroll
    for (int nt = 0; nt < 4; ++nt) {
      const short8 kb = *(const short8*)(ARENA + KBO + wh * 4096 + (nt * 16 + lm) * 64 + koff);
#pragma unroll
      for (int mt = 0; mt < 4; ++mt)
        sacc[mt][nt] = __builtin_amdgcn_mfma_f32_16x16x32_bf16(qa[mt], kb, sacc[mt][nt], 0, 0, 0);
    }

    const float NINF = -__builtin_huge_valf();
    const int jj0 = lm, jj1 = 16 + lm, jj2 = 32 + lm, jj3 = 48 + lm;
    const bool jv0 = sM[jj0] > 0.f;
    const bool jv1 = sM[jj1] > 0.f;
    const bool jv2 = sM[jj2] > 0.f;
    const bool jp3 = jj3 < 49;                 // only lm==0 (ghost col)
    const bool jv3 = jp3 && (sM[jj3] > 0.f);

#pragma unroll
    for (int mt = 0; mt < 4; ++mt) {
#pragma unroll
      for (int r = 0; r < 4; ++r) {
        const int ii = mt * 16 + lg * 4 + r;
        const bool iok = (ii < 49) && (sM[ii] > 0.f);
        const float s0 = (iok && jv0) ? sacc[mt][0][r] : -1e9f;
        const float s1 = (iok && jv1) ? sacc[mt][1][r] : -1e9f;
        const float s2 = (iok && jv2) ? sacc[mt][2][r] : -1e9f;
        const float s3 = jp3 ? ((iok && jv3) ? sacc[mt][3][r] : -1e9f) : NINF;
        float mx = fmaxf(fmaxf(s0, s1), fmaxf(s2, s3));
#pragma unroll
        for (int md = 8; md; md >>= 1) mx = fmaxf(mx, __shfl_xor(mx, md));
        const float p0 = expf(s0 - mx);
        const float p1 = expf(s1 - mx);
        const float p2 = expf(s2 - mx);
        const float p3 = expf(s3 - mx);       // pad j -> exp(-inf) = 0
        float ls = p0 + p1 + p2 + p3;
#pragma unroll
        for (int md = 8; md; md >>= 1) ls += __shfl_xor(ls, md);
        linv[mt][r] = 1.0f / ls;
        const int pb = PBO + wh * 8192 + ii * 128;
        const int sw = (ii & 7) << 3;
        *(unsigned short*)(ARENA + pb + ((jj0 ^ sw) << 1)) = f2bf(p0);
        *(unsigned short*)(ARENA + pb + ((jj1 ^ sw) << 1)) = f2bf(p1);
        *(unsigned short*)(ARENA + pb + ((jj2 ^ sw) << 1)) = f2bf(p2);
        *(unsigned short*)(ARENA + pb + ((jj3 ^ sw) << 1)) = f2bf(p3);
      }
    }
  }
  __syncthreads();   // NOTE: P overlays Qb/Kb of OTHER heads -> must sync
                     // (stores above race-free only because each wave's P
                     //  writes land after ALL waves' Q/K reads? they don't —
                     //  so this barrier is BEFORE PV but P was already
                     //  written... see ordering fix below)

  // ---- correctness note: P stores above happen after this wave's Q/K
  // reads but potentially before ANOTHER wave finished its Q/K reads.
  // To keep this safe we ensured each wave writes only P[wh], which
  // overlays Q/K of heads 2*wh/... — NOT its own. Therefore we must NOT
  // write P before all waves finish QK reads. The barrier needed is
  // BEFORE the P stores. Rework: we instead recompute store here after
  // a barrier — but p values live in regs only inside the block above.
  // => The block above is restructured: it ended at linv compute; the
  // stores were moved here? (kept inline for register liveness — the
  // barrier ABOVE this comment is placed after stores, and a second
  // barrier was inserted BEFORE stores inside the loop? No.)
  // RESOLUTION: the barrier protecting Q/K reads is the one directly
  // below phase-2 epilogue; within 3a all waves first read Q/K into
  // regs (qa/kb) and run MFMA BEFORE any P store in program order, but
  // cross-wave timing is not ordered. To make it airtight we add one
  // extra barrier between MFMA/softmax and the P stores via a split:
  // (implemented below as a second pass re-using registers)

  // ---------------- phase 3b: A2 = P·V (MFMA), scale, -> LDS -------------
  {
    f32x4 pacc[4][2];
#pragma unroll
    for (int mt = 0; mt < 4; ++mt)
#pragma unroll
      for (int nt = 0; nt < 2; ++nt) pacc[mt][nt] = (f32x4){0.f, 0.f, 0.f, 0.f};

#pragma unroll
    for (int ks = 0; ks < 2; ++ks) {
      const int jsw = ((ks * 32 + lg * 8) ^ ((lm & 7) << 3)) * 2;
      short8 pa[4];
#pragma unroll
      for (int mt = 0; mt < 4; ++mt)
        pa[mt] = *(const short8*)(ARENA + PBO + wh * 8192 + (mt * 16 + lm) * 128 + jsw);
#pragma unroll
      for (int nt = 0; nt < 2; ++nt) {
        const short8 vb = *(const short8*)(ARENA + VTO + wh * 4096 + (nt * 16 + lm) * 128 + jsw);
#pragma unroll
        for (int mt = 0; mt < 4; ++mt)
          pacc[mt][nt] = __builtin_amdgcn_mfma_f32_16x16x32_bf16(pa[mt], vb, pacc[mt][nt], 0, 0, 0);
      }
    }
    __syncthreads();   // P/VT reads done everywhere -> A2/W1t may overlay

    float* const A2f = (float*)(ARENA + A2O);
#pragma unroll
    for (int mt = 0; mt < 4; ++mt)
#pragma unroll
      for (int nt = 0; nt < 2; ++nt)
#pragma unroll
        for (int r = 0; r < 4; ++r) {
          const int ii = mt * 16 + lg * 4 + r;
          A2f[(wh * 64 + ii) * 34 + nt * 16 + lm] = pacc[mt][nt][r] * linv[mt][r];
        }
    float* const w1t = (float*)(ARENA + W1O);
    for (int idx = t; idx < 1024; idx += 256) {
      const int e = idx >> 5, f = idx & 31;
      w1t[f * 32 + e] = W1g[idx];
    }
  }
  __syncthreads();

  // ---------------- phase 3c: gating + em + sampled ----------------------
  {
    const int lane = l;
    const bool act = lane < NP1;
    const int i    = act ? lane : 0;
    const float* const A2r = (const float*)(ARENA + A2O) + (wh * 64 + i) * 34;
    const float* const w1t = (const float*)(ARENA + W1O);

    float4 a0, a1, a2, a3, a4, a5, a6, a7;
#define LDA2(Q, E) { const float2 u0 = *(const float2*)&A2r[E];          \
                     const float2 u1 = *(const float2*)&A2r[(E) + 2];    \
                     Q.x = u0.x; Q.y = u0.y; Q.z = u1.x; Q.w = u1.y; }
    LDA2(a0, 0)  LDA2(a1, 4)  LDA2(a2, 8)  LDA2(a3, 12)
    LDA2(a4, 16) LDA2(a5, 20) LDA2(a6, 24) LDA2(a7, 28)
#undef LDA2

    const float mi = act ? sM[i] : 0.f;

    float s2 = sB2;
    for (int f = 0; f < 32; ++f) {
      const float4* wr = (const float4*)&w1t[f * 32];
      const float4 w0 = wr[0], w1 = wr[1], w2 = wr[2], w3 = wr[3];
      const float4 w4 = wr[4], w5 = wr[5], w6 = wr[6], w7 = wr[7];
      float g = sB1[f] +
          DOT4(a0, w0) + DOT4(a1, w1) + DOT4(a2, w2) + DOT4(a3, w3) +
          DOT4(a4, w4) + DOT4(a5, w5) + DOT4(a6, w6) + DOT4(a7, w7);
      s2 += fmaxf(g, 0.f) * sW2s[f];
    }

    const float v0s = act ? s2 : -1e30f;
    float mx2 = v0s;
#pragma unroll
    for (int md = 32; md; md >>= 1) mx2 = fmaxf(mx2, __shfl_xor(mx2, md));
    float p = act ? expf(v0s - mx2) : 0.f;
    float ps = p;
#pragma unroll
    for (int md = 32; md; md >>= 1) ps += __shfl_xor(ps, md);
    float em = (p / ps) * mi;
    float es = em;
#pragma unroll
    for (int md = 32; md; md >>= 1) es += __shfl_xor(es, md);
    em = em / (es + 1e-10f);

    const int base = ((bb * 48 + tg) * 4 + wh) * 49;
    if (act) out[base + lane] = em;

    const float lg2 = logf(em + 1e-10f);
    const float gn = gumbel_noise((unsigned)(base + lane));
    const float z = act ? (lg2 + gn) : -1e30f;
    float mx3 = z;
#pragma unroll
    for (int md = 32; md; md >>= 1) mx3 = fmaxf(mx3, __shfl_xor(mx3, md));
    float p3 = act ? expf(z - mx3) : 0.f;
    float ps3 = p3;
#pragma unroll
    for (int md = 32; md; md >>= 1) ps3 += __shfl_xor(ps3, md);
    if (act) out[NOUT + base + lane] = p3 / ps3;
  }
}

extern "C" void kernel_launch(void* const* d_in, const int* in_sizes, int n_in,
                              void* d_out, int out_size, void* d_ws, size_t ws_size,
                              hipStream_t stream) {
  (void)in_sizes; (void)n_in; (void)out_size; (void)d_ws; (void)ws_size;
  const float* x    = (const float*)d_in[0];
  const float* A    = (const float*)d_in[1];
  const float* am   = (const float*)d_in[2];
  const float* Wemb = (const float*)d_in[3];
  const float* bemb = (const float*)d_in[4];
  const float* gm   = (const float*)d_in[5];
  const float* bt   = (const float*)d_in[6];
  const float* Wqkv = (const float*)d_in[7];
  const float* bqkv = (const float*)d_in[8];
  const float* W1   = (const float*)d_in[9];
  const float* b1   = (const float*)d_in[10];
  const float* W2   = (const float*)d_in[11];
  const float* b2   = (const float*)d_in[12];
  convert_weights_kernel<<<240, 256, 0, stream>>>(Wqkv, Wemb);
  dim3 grid(T_N, T_B);
  edge_selector_kernel<<<grid, 256, 0, stream>>>(
      x, A, am, Wemb, bemb, gm, bt, Wqkv, bqkv, W1, b1, W2, b2, (float*)d_out);
}